// Round 2
// baseline (169.150 us; speedup 1.0000x reference)
//
#include <hip/hip_runtime.h>
#include <hip/hip_bf16.h>

// SAGAN self-attention, B=16, C=128, H=W=64. Inputs fp32, output fp32.
// ws layout in ushorts (bf16):
//   U_WN  = 0        : Wn bf16 [96][128] (theta 0..15, phi 16..31, g 32..95)
//   U_WO  = 12288    : Wo bf16 [128][64]
//   U_TH  = 20480    : thetaT bf16 [16 b][4096 s][16 c]
//   U_PHI = 1069056  : phiT   bf16 [16 b][1024 t][16 c]
//   U_G   = 1331200  : g      bf16 [16 b][64 c][1024 t]
//   U_OT  = 2379776  : oT     bf16 [16 b][4096 s][64 c]

#define U_WN  0
#define U_WO  12288
#define U_TH  20480
#define U_PHI 1069056
#define U_G   1331200
#define U_OT  2379776

typedef __attribute__((ext_vector_type(8))) short bf16x8;
typedef __attribute__((ext_vector_type(4))) short s16x4;
typedef __attribute__((ext_vector_type(4))) float f32x4;
typedef __attribute__((ext_vector_type(16))) float f32x16;

__device__ inline unsigned short f2b(float f) {
    union { float f; unsigned u; } v; v.f = f;
    unsigned r = v.u + 0x7FFFu + ((v.u >> 16) & 1u);   // RNE
    return (unsigned short)(r >> 16);
}
__device__ inline float b2f(unsigned short u) {
    union { unsigned u; float f; } v; v.u = ((unsigned)u) << 16; return v.f;
}

// pack two f32 -> one u32 of 2 bf16 (RNE). s_nop guards trans->VALU hazard
// (producer may be v_exp_f32 from __expf; compiler can't see into asm).
__device__ inline unsigned cvtpk_bf16(float lo, float hi) {
    unsigned r;
    asm("s_nop 0\n\tv_cvt_pk_bf16_f32 %0, %1, %2" : "=v"(r) : "v"(lo), "v"(hi));
    return r;
}
// v_permlane32_swap_b32 a, b:
//   a' = {lanes 0-31: a_lo, lanes 32-63: b_lo}
//   b' = {lanes 0-31: a_hi, lanes 32-63: b_hi}
// s_nop before/after guards VALU<->permlane / permlane->MFMA wait states.
__device__ inline void pl32swap(unsigned &a, unsigned &b) {
    asm("s_nop 1\n\tv_permlane32_swap_b32 %0, %1\n\ts_nop 1" : "+v"(a), "+v"(b));
}

// ---------------- Kernel A: spectral norm, emit bf16 weights ----------------
__global__ __launch_bounds__(256) void sn4(
        const float* __restrict__ w0, const float* __restrict__ w1,
        const float* __restrict__ w2, const float* __restrict__ w3,
        const float* __restrict__ u0, const float* __restrict__ u1,
        const float* __restrict__ u2, const float* __restrict__ u3,
        unsigned short* __restrict__ wsu) {
    int wi = blockIdx.x;
    const float* W; const float* u; unsigned short* dst; int on, in_;
    if      (wi == 0) { W = w0; u = u0; dst = wsu;          on = 16;  in_ = 128; }
    else if (wi == 1) { W = w1; u = u1; dst = wsu + 2048;   on = 16;  in_ = 128; }
    else if (wi == 2) { W = w2; u = u2; dst = wsu + 4096;   on = 64;  in_ = 128; }
    else              { W = w3; u = u3; dst = wsu + 12288;  on = 128; in_ = 64;  }
    __shared__ float Wl[8320];    // [on][in_+1], max(128*65, 64*129) = 8320
    __shared__ float ul[128];
    __shared__ float v[128];
    __shared__ float red[256];
    __shared__ float s_inv;
    int tid = threadIdx.x;
    int n = on * in_;
    int stride = in_ + 1;
    int shift = (in_ == 128) ? 7 : 6;
    int mask = in_ - 1;
    for (int i = tid; i < n; i += 256) {
        int o = i >> shift, j = i & mask;
        Wl[o * stride + j] = W[i];
    }
    if (tid < on) ul[tid] = u[tid];
    __syncthreads();
    float vi = 0.f;
    if (tid < in_) {
        for (int o = 0; o < on; ++o) vi += ul[o] * Wl[o * stride + tid];
    }
    red[tid] = (tid < in_) ? vi * vi : 0.f;
    __syncthreads();
    for (int st = 128; st > 0; st >>= 1) {
        if (tid < st) red[tid] += red[tid + st];
        __syncthreads();
    }
    float inv_nv = 1.0f / fmaxf(sqrtf(red[0]), 1e-12f);
    __syncthreads();
    if (tid < in_) v[tid] = vi * inv_nv;
    __syncthreads();
    float ui = 0.f;
    if (tid < on) {
        for (int i = 0; i < in_; ++i) ui += v[i] * Wl[tid * stride + i];
    }
    red[tid] = (tid < on) ? ui * ui : 0.f;
    __syncthreads();
    for (int st = 128; st > 0; st >>= 1) {
        if (tid < st) red[tid] += red[tid + st];
        __syncthreads();
    }
    if (tid == 0) {
        float nsq = red[0];
        float sv = nsq / fmaxf(sqrtf(nsq), 1e-12f);
        s_inv = 1.0f / sv;
    }
    __syncthreads();
    float inv = s_inv;
    for (int e = tid; e < n; e += 256) {
        int o = e >> shift, j = e & mask;
        dst[e] = f2b(Wl[o * stride + j] * inv);
    }
}

// ------- Kernel B: MFMA conv + 2x2 maxpool (unchanged this round) -----------
__global__ __launch_bounds__(256, 2) void convpool_mfma(
        const float* __restrict__ x, const unsigned short* __restrict__ wn,
        unsigned short* __restrict__ thetaT, unsigned short* __restrict__ phiT,
        unsigned short* __restrict__ gT) {
    __shared__ unsigned short xT[128 * 136];   // [px][c], stride 136
    __shared__ unsigned short wnl[96 * 136];   // [oc][c], stride 136; reused as poolbuf
    int tid = threadIdx.x;
    int bb = blockIdx.x >> 5, tile = blockIdx.x & 31;
    int px0 = tile << 7;
    for (int i = tid; i < 1536; i += 256) {
        int r = i >> 4, c8 = (i & 15) * 8;
        *(bf16x8*)&wnl[r * 136 + c8] = *(const bf16x8*)&wn[r * 128 + c8];
    }
    const float4* x4 = (const float4*)x;
    {
        int p4 = tid & 31, cg = (tid >> 5) * 4;
        for (int k = 0; k < 4; ++k) {
            int cb = k * 32 + cg;
            float4 v0 = x4[(bb * 128 + cb + 0) * 1024 + tile * 32 + p4];
            float4 v1 = x4[(bb * 128 + cb + 1) * 1024 + tile * 32 + p4];
            float4 v2 = x4[(bb * 128 + cb + 2) * 1024 + tile * 32 + p4];
            float4 v3 = x4[(bb * 128 + cb + 3) * 1024 + tile * 32 + p4];
            float a0[4] = {v0.x, v0.y, v0.z, v0.w};
            float a1[4] = {v1.x, v1.y, v1.z, v1.w};
            float a2[4] = {v2.x, v2.y, v2.z, v2.w};
            float a3[4] = {v3.x, v3.y, v3.z, v3.w};
#pragma unroll
            for (int j = 0; j < 4; ++j) {
                s16x4 u; u[0] = (short)f2b(a0[j]); u[1] = (short)f2b(a1[j]);
                u[2] = (short)f2b(a2[j]); u[3] = (short)f2b(a3[j]);
                *(s16x4*)&xT[(p4 * 4 + j) * 136 + cb] = u;
            }
        }
    }
    __syncthreads();
    int lane = tid & 63, wv = tid >> 6;
    int q = lane >> 4, l = lane & 15;
    int pxw = wv * 32;
    f32x4 acc[2][6];
    const f32x4 z4 = {0.f, 0.f, 0.f, 0.f};
#pragma unroll
    for (int mt = 0; mt < 2; ++mt)
#pragma unroll
        for (int nt = 0; nt < 6; ++nt) acc[mt][nt] = z4;
#pragma unroll
    for (int kk = 0; kk < 4; ++kk) {
        bf16x8 a0 = *(const bf16x8*)&xT[(pxw + l) * 136 + kk * 32 + q * 8];
        bf16x8 a1 = *(const bf16x8*)&xT[(pxw + 16 + l) * 136 + kk * 32 + q * 8];
#pragma unroll
        for (int nt = 0; nt < 6; ++nt) {
            bf16x8 bw = *(const bf16x8*)&wnl[(nt * 16 + l) * 136 + kk * 32 + q * 8];
            acc[0][nt] = __builtin_amdgcn_mfma_f32_16x16x32_bf16(a0, bw, acc[0][nt], 0, 0, 0);
            acc[1][nt] = __builtin_amdgcn_mfma_f32_16x16x32_bf16(a1, bw, acc[1][nt], 0, 0, 0);
        }
    }
#pragma unroll
    for (int mt = 0; mt < 2; ++mt)
#pragma unroll
        for (int r = 0; r < 4; ++r) {
            int s = px0 + pxw + mt * 16 + q * 4 + r;
            thetaT[(bb * 4096 + s) * 16 + l] = f2b(acc[mt][0][r]);
        }
    __syncthreads();   // all waves done reading wnl
    unsigned short* poolbuf = wnl;   // [80 ch][px] stride 132
#pragma unroll
    for (int mt = 0; mt < 2; ++mt)
#pragma unroll
        for (int nt = 1; nt < 6; ++nt) {
            int ch = nt * 16 + l - 16;
#pragma unroll
            for (int r = 0; r < 4; ++r) {
                poolbuf[ch * 132 + pxw + mt * 16 + q * 4 + r] = f2b(acc[mt][nt][r]);
            }
        }
    __syncthreads();
    for (int i = tid; i < 2560; i += 256) {
        int tcol = i & 31, ch = i >> 5;
        int base = ch * 132 + tcol * 2;
        float m0 = fmaxf(b2f(poolbuf[base]), b2f(poolbuf[base + 1]));
        float m1 = fmaxf(b2f(poolbuf[base + 64]), b2f(poolbuf[base + 65]));
        float m = fmaxf(m0, m1);
        int t = tile * 32 + tcol;
        if (ch < 16) phiT[(bb * 1024 + t) * 16 + ch] = f2b(m);
        else         gT[(bb * 64 + ch - 16) * 1024 + t] = f2b(m);
    }
}

// ------- Kernel C: MFMA fused attention — barrier-free, LDS-free ------------
// grid: 16 b x 32 s-tiles (128 s) = 512 blocks, 4 independent waves x 32 s.
// S^T[t][s] = mfma_32x32x16(A=phi rows t, B=theta cols s): K=16, no padding.
// D layout (m74/m101): col = lane&31 = s (one s per lane!), row = t =
// (reg&3)+8*(reg>>2)+4*(lane>>5). exp in-register; P->bf16 B-frag via
// cvt_pk + permlane32_swap (swap(u0,u2)->(w0,w2), swap(u1,u3)->(w1,w3)).
// PV: O[c][? ] = mfma(A=g rows c, B=P): D col = s again -> softmax
// denominator is lane-local (one shfl_xor(32)). Direct b128 global stores.
__global__ __launch_bounds__(256, 2) void attn_mfma(
        const unsigned short* __restrict__ thetaT,
        const unsigned short* __restrict__ phiT,
        const unsigned short* __restrict__ gT,
        unsigned short* __restrict__ oT) {
    int tid = threadIdx.x;
    int bb = blockIdx.x >> 5, st = blockIdx.x & 31;
    int s0 = st << 7;
    int lane = tid & 63, wv = tid >> 6;
    int sl = lane & 31, hi = lane >> 5;
    int srow = bb * 4096 + s0 + wv * 32 + sl;      // this lane's s (global)
    const unsigned short* phiB = phiT + bb * 16384;    // [1024][16]
    const unsigned short* gB   = gT + bb * 65536;      // [64][1024]

    // theta B-frag: B[k=c=hi*8+j][col=s=sl], contiguous bf16x8, loop-invariant
    bf16x8 bth = *(const bf16x8*)&thetaT[srow * 16 + hi * 8];

    f32x16 z16;
#pragma unroll
    for (int i = 0; i < 16; ++i) z16[i] = 0.f;
    f32x16 acc0 = z16, acc1 = z16;     // O cols c 0..31 / 32..63 (rows), s=sl
    float lp4[4] = {0.f, 0.f, 0.f, 0.f};

    // phi A-frag 1-deep pipeline: A[row=t=sl (+32mt)][k=c=hi*8+j]
    bf16x8 ph0 = *(const bf16x8*)&phiB[(sl) * 16 + hi * 8];
    bf16x8 ph1 = *(const bf16x8*)&phiB[(32 + sl) * 16 + hi * 8];

    for (int tc = 0; tc < 16; ++tc) {
        int t0 = tc << 6;
        // g A-frags for PV: A[row=c=sl(+32)][k=t], issued early, used late
        bf16x8 gf0[4], gf1[4];
#pragma unroll
        for (int kt = 0; kt < 4; ++kt) {
            gf0[kt] = *(const bf16x8*)&gB[(sl) * 1024 + t0 + kt * 16 + hi * 8];
            gf1[kt] = *(const bf16x8*)&gB[(32 + sl) * 1024 + t0 + kt * 16 + hi * 8];
        }
        // S^T tiles: t-block t0+0..31 (sa0), t0+32..63 (sa1)
        f32x16 sa0 = __builtin_amdgcn_mfma_f32_32x32x16_bf16(ph0, bth, z16, 0, 0, 0);
        f32x16 sa1 = __builtin_amdgcn_mfma_f32_32x32x16_bf16(ph1, bth, z16, 0, 0, 0);
        // prefetch next iteration's phi (tc=15 wraps to 0, value unused)
        int t0n = ((tc + 1) & 15) << 6;
        ph0 = *(const bf16x8*)&phiB[(t0n + sl) * 16 + hi * 8];
        ph1 = *(const bf16x8*)&phiB[(t0n + 32 + sl) * 16 + hi * 8];
        // P = exp(S): lane holds t = base + (reg&3)+8*(reg>>2)+4*hi, s = sl
        unsigned u0[8], u1[8];
#pragma unroll
        for (int i = 0; i < 8; ++i) {
            float e0 = __expf(sa0[2 * i]);
            float e1 = __expf(sa0[2 * i + 1]);
            float e2 = __expf(sa1[2 * i]);
            float e3 = __expf(sa1[2 * i + 1]);
            lp4[0] += e0; lp4[1] += e1; lp4[2] += e2; lp4[3] += e3;
            u0[i] = cvtpk_bf16(e0, e1);    // t-pairs (0,1),(2,3),(8,9),(10,11),
            u1[i] = cvtpk_bf16(e2, e3);    //         (16,17),(18,19),(24,25),(26,27) +4hi
        }
        // B-frag assembly: word w = t-pair (hi*8+2w, hi*8+2w+1) per K=16 chunk
        pl32swap(u0[0], u0[2]); pl32swap(u0[1], u0[3]);
        pl32swap(u0[4], u0[6]); pl32swap(u0[5], u0[7]);
        pl32swap(u1[0], u1[2]); pl32swap(u1[1], u1[3]);
        pl32swap(u1[4], u1[6]); pl32swap(u1[5], u1[7]);
        // PV: k-chunk ktg covers t0+ktg*16..+15; B-frag words:
        //   ktg0: u0[0..3], ktg1: u0[4..7], ktg2: u1[0..3], ktg3: u1[4..7]
        {
            union { unsigned w[4]; bf16x8 v; } pf = {{u0[0], u0[1], u0[2], u0[3]}};
            acc0 = __builtin_amdgcn_mfma_f32_32x32x16_bf16(gf0[0], pf.v, acc0, 0, 0, 0);
            acc1 = __builtin_amdgcn_mfma_f32_32x32x16_bf16(gf1[0], pf.v, acc1, 0, 0, 0);
        }
        {
            union { unsigned w[4]; bf16x8 v; } pf = {{u0[4], u0[5], u0[6], u0[7]}};
            acc0 = __builtin_amdgcn_mfma_f32_32x32x16_bf16(gf0[1], pf.v, acc0, 0, 0, 0);
            acc1 = __builtin_amdgcn_mfma_f32_32x32x16_bf16(gf1[1], pf.v, acc1, 0, 0, 0);
        }
        {
            union { unsigned w[4]; bf16x8 v; } pf = {{u1[0], u1[1], u1[2], u1[3]}};
            acc0 = __builtin_amdgcn_mfma_f32_32x32x16_bf16(gf0[2], pf.v, acc0, 0, 0, 0);
            acc1 = __builtin_amdgcn_mfma_f32_32x32x16_bf16(gf1[2], pf.v, acc1, 0, 0, 0);
        }
        {
            union { unsigned w[4]; bf16x8 v; } pf = {{u1[4], u1[5], u1[6], u1[7]}};
            acc0 = __builtin_amdgcn_mfma_f32_32x32x16_bf16(gf0[3], pf.v, acc0, 0, 0, 0);
            acc1 = __builtin_amdgcn_mfma_f32_32x32x16_bf16(gf1[3], pf.v, acc1, 0, 0, 0);
        }
    }
    // softmax denominator: lane-local partials + partner half (lane^32)
    float tot = (lp4[0] + lp4[1]) + (lp4[2] + lp4[3]);
    tot += __shfl_xor(tot, 32);
    float inv = 1.0f / tot;
    // O rows at lane: c = (reg&3)+8*(reg>>2)+4*hi (+32 for acc1), s = sl.
    // Same pk+swap trick assembles contiguous 8-c runs for b128 stores.
    unsigned o0[8], o1[8];
#pragma unroll
    for (int i = 0; i < 8; ++i) {
        o0[i] = cvtpk_bf16(acc0[2 * i] * inv, acc0[2 * i + 1] * inv);
        o1[i] = cvtpk_bf16(acc1[2 * i] * inv, acc1[2 * i + 1] * inv);
    }
    pl32swap(o0[0], o0[2]); pl32swap(o0[1], o0[3]);
    pl32swap(o0[4], o0[6]); pl32swap(o0[5], o0[7]);
    pl32swap(o1[0], o1[2]); pl32swap(o1[1], o1[3]);
    pl32swap(o1[4], o1[6]); pl32swap(o1[5], o1[7]);
    unsigned short* orow = oT + srow * 64;
    {
        union { unsigned w[4]; bf16x8 v; } ow = {{o0[0], o0[1], o0[2], o0[3]}};
        *(bf16x8*)&orow[hi * 8] = ow.v;            // c = hi*8 .. +7
    }
    {
        union { unsigned w[4]; bf16x8 v; } ow = {{o0[4], o0[5], o0[6], o0[7]}};
        *(bf16x8*)&orow[16 + hi * 8] = ow.v;       // c = 16+hi*8 .. +7
    }
    {
        union { unsigned w[4]; bf16x8 v; } ow = {{o1[0], o1[1], o1[2], o1[3]}};
        *(bf16x8*)&orow[32 + hi * 8] = ow.v;       // c = 32+hi*8 .. +7
    }
    {
        union { unsigned w[4]; bf16x8 v; } ow = {{o1[4], o1[5], o1[6], o1[7]}};
        *(bf16x8*)&orow[48 + hi * 8] = ow.v;       // c = 48+hi*8 .. +7
    }
}

// ------- Kernel D: out = gamma * (Wo @ o) + x  (MFMA, unchanged) ------------
__global__ __launch_bounds__(256, 2) void outconv_mfma(
        const unsigned short* __restrict__ oT, const unsigned short* __restrict__ wo,
        const float* __restrict__ x, const float* __restrict__ gam,
        float* __restrict__ out) {
    __shared__ unsigned short wol[128 * 72];   // [oc][c] stride 72
    int tid = threadIdx.x;
    int bb = blockIdx.x >> 4, tile = blockIdx.x & 15;
    int lane = tid & 63, wv = tid >> 6;
    int q = lane >> 4, l = lane & 15;
    int pxw = tile * 256 + wv * 64;
    for (int i = tid; i < 1024; i += 256) {
        int r = i >> 3, c8 = (i & 7) * 8;
        *(bf16x8*)&wol[r * 72 + c8] = *(const bf16x8*)&wo[r * 64 + c8];
    }
    bf16x8 af[4][2];
#pragma unroll
    for (int mt = 0; mt < 4; ++mt)
#pragma unroll
        for (int kk = 0; kk < 2; ++kk)
            af[mt][kk] = *(const bf16x8*)&oT[(bb * 4096 + pxw + mt * 16 + l) * 64 + kk * 32 + q * 8];
    __syncthreads();
    f32x4 acc[4][8];
    const f32x4 z4 = {0.f, 0.f, 0.f, 0.f};
#pragma unroll
    for (int mt = 0; mt < 4; ++mt)
#pragma unroll
        for (int nt = 0; nt < 8; ++nt) acc[mt][nt] = z4;
#pragma unroll
    for (int kk = 0; kk < 2; ++kk) {
#pragma unroll
        for (int nt = 0; nt < 8; ++nt) {
            bf16x8 bw = *(const bf16x8*)&wol[(nt * 16 + l) * 72 + kk * 32 + q * 8];
#pragma unroll
            for (int mt = 0; mt < 4; ++mt)
                acc[mt][nt] = __builtin_amdgcn_mfma_f32_16x16x32_bf16(af[mt][kk], bw, acc[mt][nt], 0, 0, 0);
        }
    }
    float gm = gam[0];
    const float4* x4 = (const float4*)x;
    float4* out4 = (float4*)out;
#pragma unroll
    for (int mt = 0; mt < 4; ++mt)
#pragma unroll
        for (int nt = 0; nt < 8; ++nt) {
            int oc = nt * 16 + l;
            int px = pxw + mt * 16 + q * 4;
            int gi = (bb * 128 + oc) * 1024 + (px >> 2);
            float4 xv = x4[gi];
            float4 r;
            r.x = gm * acc[mt][nt][0] + xv.x;
            r.y = gm * acc[mt][nt][1] + xv.y;
            r.z = gm * acc[mt][nt][2] + xv.z;
            r.w = gm * acc[mt][nt][3] + xv.w;
            out4[gi] = r;
        }
}

extern "C" void kernel_launch(void* const* d_in, const int* in_sizes, int n_in,
                              void* d_out, int out_size, void* d_ws, size_t ws_size,
                              hipStream_t stream) {
    const float* x  = (const float*)d_in[0];
    const float* wt = (const float*)d_in[1];
    const float* wp = (const float*)d_in[2];
    const float* wg = (const float*)d_in[3];
    const float* wo = (const float*)d_in[4];
    const float* ut = (const float*)d_in[5];
    const float* up = (const float*)d_in[6];
    const float* ug = (const float*)d_in[7];
    const float* uo = (const float*)d_in[8];
    const float* gm = (const float*)d_in[9];
    unsigned short* wsu = (unsigned short*)d_ws;
    float* out = (float*)d_out;

    sn4<<<4, 256, 0, stream>>>(wt, wp, wg, wo, ut, up, ug, uo, wsu);
    convpool_mfma<<<512, 256, 0, stream>>>(x, wsu + U_WN,
                                           wsu + U_TH, wsu + U_PHI, wsu + U_G);
    attn_mfma<<<512, 256, 0, stream>>>(wsu + U_TH, wsu + U_PHI, wsu + U_G, wsu + U_OT);
    outconv_mfma<<<256, 256, 0, stream>>>(wsu + U_OT, wsu + U_WO, x, gm, out);
}

// Round 3
// 163.607 us; speedup vs baseline: 1.0339x; 1.0339x over previous
//
#include <hip/hip_runtime.h>
#include <hip/hip_bf16.h>

// SAGAN self-attention, B=16, C=128, H=W=64. Inputs fp32, output fp32.
// ws layout in ushorts (bf16):
//   U_WN  = 0        : Wn bf16 [96][128] (theta 0..15, phi 16..31, g 32..95)
//   U_WO  = 12288    : Wo bf16 [128][64]
//   U_TH  = 20480    : thetaT bf16 [16 b][4096 s][16 c]
//   U_PHI = 1069056  : phiT   bf16 [16 b][1024 t][16 c]
//   U_G   = 1331200  : g      bf16 [16 b][64 c][1024 t]
//   U_OT  = 2379776  : oT     bf16 [16 b][4096 s][64 c]

#define U_WN  0
#define U_WO  12288
#define U_TH  20480
#define U_PHI 1069056
#define U_G   1331200
#define U_OT  2379776

typedef __attribute__((ext_vector_type(8))) short bf16x8;
typedef __attribute__((ext_vector_type(4))) short s16x4;
typedef __attribute__((ext_vector_type(4))) float f32x4;
typedef __attribute__((ext_vector_type(16))) float f32x16;

__device__ inline unsigned short f2b(float f) {
    union { float f; unsigned u; } v; v.f = f;
    unsigned r = v.u + 0x7FFFu + ((v.u >> 16) & 1u);   // RNE
    return (unsigned short)(r >> 16);
}
__device__ inline float b2f(unsigned short u) {
    union { unsigned u; float f; } v; v.u = ((unsigned)u) << 16; return v.f;
}

// pack two f32 -> one u32 of 2 bf16 (RNE; lo = first arg). s_nop guards
// trans->VALU hazard (producer may be v_exp_f32).
__device__ inline unsigned cvtpk_bf16(float lo, float hi) {
    unsigned r;
    asm("s_nop 0\n\tv_cvt_pk_bf16_f32 %0, %1, %2" : "=v"(r) : "v"(lo), "v"(hi));
    return r;
}
// v_permlane32_swap_b32: exchanges lane halves between a and b
// (mapping verified end-to-end by the passing round-2 build).
__device__ inline void pl32swap(unsigned &a, unsigned &b) {
    asm("s_nop 1\n\tv_permlane32_swap_b32 %0, %1\n\ts_nop 1" : "+v"(a), "+v"(b));
}

// ---------------- Kernel A: spectral norm, emit bf16 weights ----------------
__global__ __launch_bounds__(256) void sn4(
        const float* __restrict__ w0, const float* __restrict__ w1,
        const float* __restrict__ w2, const float* __restrict__ w3,
        const float* __restrict__ u0, const float* __restrict__ u1,
        const float* __restrict__ u2, const float* __restrict__ u3,
        unsigned short* __restrict__ wsu) {
    int wi = blockIdx.x;
    const float* W; const float* u; unsigned short* dst; int on, in_;
    if      (wi == 0) { W = w0; u = u0; dst = wsu;          on = 16;  in_ = 128; }
    else if (wi == 1) { W = w1; u = u1; dst = wsu + 2048;   on = 16;  in_ = 128; }
    else if (wi == 2) { W = w2; u = u2; dst = wsu + 4096;   on = 64;  in_ = 128; }
    else              { W = w3; u = u3; dst = wsu + 12288;  on = 128; in_ = 64;  }
    __shared__ float Wl[8320];    // [on][in_+1], max(128*65, 64*129) = 8320
    __shared__ float ul[128];
    __shared__ float v[128];
    __shared__ float red[256];
    __shared__ float s_inv;
    int tid = threadIdx.x;
    int n = on * in_;
    int stride = in_ + 1;
    int shift = (in_ == 128) ? 7 : 6;
    int mask = in_ - 1;
    for (int i = tid; i < n; i += 256) {
        int o = i >> shift, j = i & mask;
        Wl[o * stride + j] = W[i];
    }
    if (tid < on) ul[tid] = u[tid];
    __syncthreads();
    float vi = 0.f;
    if (tid < in_) {
        for (int o = 0; o < on; ++o) vi += ul[o] * Wl[o * stride + tid];
    }
    red[tid] = (tid < in_) ? vi * vi : 0.f;
    __syncthreads();
    for (int st = 128; st > 0; st >>= 1) {
        if (tid < st) red[tid] += red[tid + st];
        __syncthreads();
    }
    float inv_nv = 1.0f / fmaxf(sqrtf(red[0]), 1e-12f);
    __syncthreads();
    if (tid < in_) v[tid] = vi * inv_nv;
    __syncthreads();
    float ui = 0.f;
    if (tid < on) {
        for (int i = 0; i < in_; ++i) ui += v[i] * Wl[tid * stride + i];
    }
    red[tid] = (tid < on) ? ui * ui : 0.f;
    __syncthreads();
    for (int st = 128; st > 0; st >>= 1) {
        if (tid < st) red[tid] += red[tid + st];
        __syncthreads();
    }
    if (tid == 0) {
        float nsq = red[0];
        float sv = nsq / fmaxf(sqrtf(nsq), 1e-12f);
        s_inv = 1.0f / sv;
    }
    __syncthreads();
    float inv = s_inv;
    for (int e = tid; e < n; e += 256) {
        int o = e >> shift, j = e & mask;
        dst[e] = f2b(Wl[o * stride + j] * inv);
    }
}

// ------- Kernel B: MFMA conv + 2x2 maxpool ----------------------------------
// grid: 16 b x 32 px-tiles (128 px = 2 image rows) = 512 blocks, 4 waves.
// Staging pack now uses v_cvt_pk_bf16_f32 (2 elems/instr) instead of 4
// scalar f2b sequences per pair.
__global__ __launch_bounds__(256, 2) void convpool_mfma(
        const float* __restrict__ x, const unsigned short* __restrict__ wn,
        unsigned short* __restrict__ thetaT, unsigned short* __restrict__ phiT,
        unsigned short* __restrict__ gT) {
    __shared__ unsigned short xT[128 * 136];   // [px][c], stride 136
    __shared__ unsigned short wnl[96 * 136];   // [oc][c], stride 136; reused as poolbuf
    int tid = threadIdx.x;
    int bb = blockIdx.x >> 5, tile = blockIdx.x & 31;
    int px0 = tile << 7;
    for (int i = tid; i < 1536; i += 256) {
        int r = i >> 4, c8 = (i & 15) * 8;
        *(bf16x8*)&wnl[r * 136 + c8] = *(const bf16x8*)&wn[r * 128 + c8];
    }
    const float4* x4 = (const float4*)x;
    {
        int p4 = tid & 31, cg = (tid >> 5) * 4;
        for (int k = 0; k < 4; ++k) {
            int cb = k * 32 + cg;
            float4 v0 = x4[(bb * 128 + cb + 0) * 1024 + tile * 32 + p4];
            float4 v1 = x4[(bb * 128 + cb + 1) * 1024 + tile * 32 + p4];
            float4 v2 = x4[(bb * 128 + cb + 2) * 1024 + tile * 32 + p4];
            float4 v3 = x4[(bb * 128 + cb + 3) * 1024 + tile * 32 + p4];
            float a0[4] = {v0.x, v0.y, v0.z, v0.w};
            float a1[4] = {v1.x, v1.y, v1.z, v1.w};
            float a2[4] = {v2.x, v2.y, v2.z, v2.w};
            float a3[4] = {v3.x, v3.y, v3.z, v3.w};
#pragma unroll
            for (int j = 0; j < 4; ++j) {
                union { unsigned w[2]; s16x4 v; } pk;
                pk.w[0] = cvtpk_bf16(a0[j], a1[j]);   // channels cb, cb+1
                pk.w[1] = cvtpk_bf16(a2[j], a3[j]);   // channels cb+2, cb+3
                *(s16x4*)&xT[(p4 * 4 + j) * 136 + cb] = pk.v;
            }
        }
    }
    __syncthreads();
    int lane = tid & 63, wv = tid >> 6;
    int q = lane >> 4, l = lane & 15;
    int pxw = wv * 32;
    f32x4 acc[2][6];
    const f32x4 z4 = {0.f, 0.f, 0.f, 0.f};
#pragma unroll
    for (int mt = 0; mt < 2; ++mt)
#pragma unroll
        for (int nt = 0; nt < 6; ++nt) acc[mt][nt] = z4;
#pragma unroll
    for (int kk = 0; kk < 4; ++kk) {
        bf16x8 a0 = *(const bf16x8*)&xT[(pxw + l) * 136 + kk * 32 + q * 8];
        bf16x8 a1 = *(const bf16x8*)&xT[(pxw + 16 + l) * 136 + kk * 32 + q * 8];
#pragma unroll
        for (int nt = 0; nt < 6; ++nt) {
            bf16x8 bw = *(const bf16x8*)&wnl[(nt * 16 + l) * 136 + kk * 32 + q * 8];
            acc[0][nt] = __builtin_amdgcn_mfma_f32_16x16x32_bf16(a0, bw, acc[0][nt], 0, 0, 0);
            acc[1][nt] = __builtin_amdgcn_mfma_f32_16x16x32_bf16(a1, bw, acc[1][nt], 0, 0, 0);
        }
    }
#pragma unroll
    for (int mt = 0; mt < 2; ++mt)
#pragma unroll
        for (int r = 0; r < 4; ++r) {
            int s = px0 + pxw + mt * 16 + q * 4 + r;
            thetaT[(bb * 4096 + s) * 16 + l] = f2b(acc[mt][0][r]);
        }
    __syncthreads();   // all waves done reading wnl
    unsigned short* poolbuf = wnl;   // [80 ch][px] stride 132
#pragma unroll
    for (int mt = 0; mt < 2; ++mt)
#pragma unroll
        for (int nt = 1; nt < 6; ++nt) {
            int ch = nt * 16 + l - 16;
#pragma unroll
            for (int r = 0; r < 4; ++r) {
                poolbuf[ch * 132 + pxw + mt * 16 + q * 4 + r] = f2b(acc[mt][nt][r]);
            }
        }
    __syncthreads();
    for (int i = tid; i < 2560; i += 256) {
        int tcol = i & 31, ch = i >> 5;
        int base = ch * 132 + tcol * 2;
        float m0 = fmaxf(b2f(poolbuf[base]), b2f(poolbuf[base + 1]));
        float m1 = fmaxf(b2f(poolbuf[base + 64]), b2f(poolbuf[base + 65]));
        float m = fmaxf(m0, m1);
        int t = tile * 32 + tcol;
        if (ch < 16) phiT[(bb * 1024 + t) * 16 + ch] = f2b(m);
        else         gT[(bb * 64 + ch - 16) * 1024 + t] = f2b(m);
    }
}

// ------- Kernel C: MFMA fused attention — t-split for occupancy -------------
// grid: 512 blocks x 512 threads (8 waves). Wave wv: s-group sg=wv&3
// (32 s each), t-half sp=wv>>2 (512 t each, 8 iters). 4096 waves total
// -> 4 waves/SIMD (50% occ) vs round-2's 2 (25%). Partials combined via
// 32KB LDS + ONE barrier. XCD swizzle: each XCD's L2 holds 2 batches'
// phi+g (320KB) instead of ~all 16 (2.6MB).
// S^T = mfma_32x32x16(A=phi, B=theta): D col = lane&31 = s. exp in-reg;
// P->B-frag via cvt_pk + permlane32_swap (verified round 2). PV:
// O = mfma(A=g, B=P), col = s again -> denom lane-local.
__global__ __launch_bounds__(512, 4) void attn_mfma(
        const unsigned short* __restrict__ thetaT,
        const unsigned short* __restrict__ phiT,
        const unsigned short* __restrict__ gT,
        unsigned short* __restrict__ oT) {
    __shared__ float ldsO[4][2048];   // [sg][c*32 + sl], 32KB
    __shared__ float ldsD[4][32];
    int tid = threadIdx.x;
    // XCD-chunked bijective swizzle (512 = 8 XCD x 64 chunks)
    int kblk = blockIdx.x;
    int vblk = (kblk & 7) * 64 + (kblk >> 3);
    int bb = vblk >> 5, st = vblk & 31;
    int s0 = st << 7;
    int lane = tid & 63, wv = tid >> 6;
    int sg = wv & 3, sp = wv >> 2;
    int sl = lane & 31, hi = lane >> 5;
    int srow = bb * 4096 + s0 + sg * 32 + sl;      // this lane's s (global)
    const unsigned short* phiB = phiT + bb * 16384;    // [1024][16]
    const unsigned short* gB   = gT + bb * 65536;      // [64][1024]
    int tbase = sp << 9;                               // 0 or 512

    // theta B-frag: B[k=c=hi*8+j][col=s=sl], loop-invariant
    bf16x8 bth = *(const bf16x8*)&thetaT[srow * 16 + hi * 8];

    f32x16 z16;
#pragma unroll
    for (int i = 0; i < 16; ++i) z16[i] = 0.f;
    f32x16 acc0 = z16, acc1 = z16;     // O rows c 0..31 / 32..63, col s=sl
    float lp4[4] = {0.f, 0.f, 0.f, 0.f};

    // phi A-frag 1-deep pipeline: A[row=t][k=c=hi*8+j]
    bf16x8 ph0 = *(const bf16x8*)&phiB[(tbase + sl) * 16 + hi * 8];
    bf16x8 ph1 = *(const bf16x8*)&phiB[(tbase + 32 + sl) * 16 + hi * 8];

    for (int tc = 0; tc < 8; ++tc) {
        int t0 = tbase + (tc << 6);
        // g A-frags for PV: A[row=c=sl(+32)][k=t], issued early, used late
        bf16x8 gf0[4], gf1[4];
#pragma unroll
        for (int kt = 0; kt < 4; ++kt) {
            gf0[kt] = *(const bf16x8*)&gB[(sl) * 1024 + t0 + kt * 16 + hi * 8];
            gf1[kt] = *(const bf16x8*)&gB[(32 + sl) * 1024 + t0 + kt * 16 + hi * 8];
        }
        // S^T tiles: t-block t0+0..31 (sa0), t0+32..63 (sa1)
        f32x16 sa0 = __builtin_amdgcn_mfma_f32_32x32x16_bf16(ph0, bth, z16, 0, 0, 0);
        f32x16 sa1 = __builtin_amdgcn_mfma_f32_32x32x16_bf16(ph1, bth, z16, 0, 0, 0);
        // prefetch next iteration's phi (wraps on last iter; value unused)
        int t0n = tbase + (((tc + 1) & 7) << 6);
        ph0 = *(const bf16x8*)&phiB[(t0n + sl) * 16 + hi * 8];
        ph1 = *(const bf16x8*)&phiB[(t0n + 32 + sl) * 16 + hi * 8];
        // P = exp(S): lane holds t = t0 + (reg&3)+8*(reg>>2)+4*hi, s = sl
        unsigned u0[8], u1[8];
#pragma unroll
        for (int i = 0; i < 8; ++i) {
            float e0 = __expf(sa0[2 * i]);
            float e1 = __expf(sa0[2 * i + 1]);
            float e2 = __expf(sa1[2 * i]);
            float e3 = __expf(sa1[2 * i + 1]);
            lp4[0] += e0; lp4[1] += e1; lp4[2] += e2; lp4[3] += e3;
            u0[i] = cvtpk_bf16(e0, e1);
            u1[i] = cvtpk_bf16(e2, e3);
        }
        // B-frag assembly (verified round 2)
        pl32swap(u0[0], u0[2]); pl32swap(u0[1], u0[3]);
        pl32swap(u0[4], u0[6]); pl32swap(u0[5], u0[7]);
        pl32swap(u1[0], u1[2]); pl32swap(u1[1], u1[3]);
        pl32swap(u1[4], u1[6]); pl32swap(u1[5], u1[7]);
        {
            union { unsigned w[4]; bf16x8 v; } pf = {{u0[0], u0[1], u0[2], u0[3]}};
            acc0 = __builtin_amdgcn_mfma_f32_32x32x16_bf16(gf0[0], pf.v, acc0, 0, 0, 0);
            acc1 = __builtin_amdgcn_mfma_f32_32x32x16_bf16(gf1[0], pf.v, acc1, 0, 0, 0);
        }
        {
            union { unsigned w[4]; bf16x8 v; } pf = {{u0[4], u0[5], u0[6], u0[7]}};
            acc0 = __builtin_amdgcn_mfma_f32_32x32x16_bf16(gf0[1], pf.v, acc0, 0, 0, 0);
            acc1 = __builtin_amdgcn_mfma_f32_32x32x16_bf16(gf1[1], pf.v, acc1, 0, 0, 0);
        }
        {
            union { unsigned w[4]; bf16x8 v; } pf = {{u1[0], u1[1], u1[2], u1[3]}};
            acc0 = __builtin_amdgcn_mfma_f32_32x32x16_bf16(gf0[2], pf.v, acc0, 0, 0, 0);
            acc1 = __builtin_amdgcn_mfma_f32_32x32x16_bf16(gf1[2], pf.v, acc1, 0, 0, 0);
        }
        {
            union { unsigned w[4]; bf16x8 v; } pf = {{u1[4], u1[5], u1[6], u1[7]}};
            acc0 = __builtin_amdgcn_mfma_f32_32x32x16_bf16(gf0[3], pf.v, acc0, 0, 0, 0);
            acc1 = __builtin_amdgcn_mfma_f32_32x32x16_bf16(gf1[3], pf.v, acc1, 0, 0, 0);
        }
    }
    // per-lane partial denominator (s = sl): reduce own 4 + partner half
    float tot = (lp4[0] + lp4[1]) + (lp4[2] + lp4[3]);
    tot += __shfl_xor(tot, 32);

    // cross-split combine via LDS (one barrier). c(i,hi) = (i&3)+8*(i>>2)+4*hi
    if (sp == 1) {
#pragma unroll
        for (int i = 0; i < 16; ++i) {
            int c = (i & 3) + 8 * (i >> 2) + 4 * hi;
            ldsO[sg][c * 32 + sl] = acc0[i];
            ldsO[sg][(32 + c) * 32 + sl] = acc1[i];
        }
        if (hi == 0) ldsD[sg][sl] = tot;
    }
    __syncthreads();
    if (sp == 1) return;
    tot += ldsD[sg][sl];
    float inv = 1.0f / tot;
#pragma unroll
    for (int i = 0; i < 16; ++i) {
        int c = (i & 3) + 8 * (i >> 2) + 4 * hi;
        acc0[i] += ldsO[sg][c * 32 + sl];
        acc1[i] += ldsO[sg][(32 + c) * 32 + sl];
    }
    // pack + store (same assembly trick as round 2)
    unsigned o0[8], o1[8];
#pragma unroll
    for (int i = 0; i < 8; ++i) {
        o0[i] = cvtpk_bf16(acc0[2 * i] * inv, acc0[2 * i + 1] * inv);
        o1[i] = cvtpk_bf16(acc1[2 * i] * inv, acc1[2 * i + 1] * inv);
    }
    pl32swap(o0[0], o0[2]); pl32swap(o0[1], o0[3]);
    pl32swap(o0[4], o0[6]); pl32swap(o0[5], o0[7]);
    pl32swap(o1[0], o1[2]); pl32swap(o1[1], o1[3]);
    pl32swap(o1[4], o1[6]); pl32swap(o1[5], o1[7]);
    unsigned short* orow = oT + srow * 64;
    {
        union { unsigned w[4]; bf16x8 v; } ow = {{o0[0], o0[1], o0[2], o0[3]}};
        *(bf16x8*)&orow[hi * 8] = ow.v;
    }
    {
        union { unsigned w[4]; bf16x8 v; } ow = {{o0[4], o0[5], o0[6], o0[7]}};
        *(bf16x8*)&orow[16 + hi * 8] = ow.v;
    }
    {
        union { unsigned w[4]; bf16x8 v; } ow = {{o1[0], o1[1], o1[2], o1[3]}};
        *(bf16x8*)&orow[32 + hi * 8] = ow.v;
    }
    {
        union { unsigned w[4]; bf16x8 v; } ow = {{o1[4], o1[5], o1[6], o1[7]}};
        *(bf16x8*)&orow[48 + hi * 8] = ow.v;
    }
}

// ------- Kernel D: out = gamma * (Wo @ o) + x  (MFMA, unchanged) ------------
__global__ __launch_bounds__(256, 2) void outconv_mfma(
        const unsigned short* __restrict__ oT, const unsigned short* __restrict__ wo,
        const float* __restrict__ x, const float* __restrict__ gam,
        float* __restrict__ out) {
    __shared__ unsigned short wol[128 * 72];   // [oc][c] stride 72
    int tid = threadIdx.x;
    int bb = blockIdx.x >> 4, tile = blockIdx.x & 15;
    int lane = tid & 63, wv = tid >> 6;
    int q = lane >> 4, l = lane & 15;
    int pxw = tile * 256 + wv * 64;
    for (int i = tid; i < 1024; i += 256) {
        int r = i >> 3, c8 = (i & 7) * 8;
        *(bf16x8*)&wol[r * 72 + c8] = *(const bf16x8*)&wo[r * 64 + c8];
    }
    bf16x8 af[4][2];
#pragma unroll
    for (int mt = 0; mt < 4; ++mt)
#pragma unroll
        for (int kk = 0; kk < 2; ++kk)
            af[mt][kk] = *(const bf16x8*)&oT[(bb * 4096 + pxw + mt * 16 + l) * 64 + kk * 32 + q * 8];
    __syncthreads();
    f32x4 acc[4][8];
    const f32x4 z4 = {0.f, 0.f, 0.f, 0.f};
#pragma unroll
    for (int mt = 0; mt < 4; ++mt)
#pragma unroll
        for (int nt = 0; nt < 8; ++nt) acc[mt][nt] = z4;
#pragma unroll
    for (int kk = 0; kk < 2; ++kk) {
#pragma unroll
        for (int nt = 0; nt < 8; ++nt) {
            bf16x8 bw = *(const bf16x8*)&wol[(nt * 16 + l) * 72 + kk * 32 + q * 8];
#pragma unroll
            for (int mt = 0; mt < 4; ++mt)
                acc[mt][nt] = __builtin_amdgcn_mfma_f32_16x16x32_bf16(af[mt][kk], bw, acc[mt][nt], 0, 0, 0);
        }
    }
    float gm = gam[0];
    const float4* x4 = (const float4*)x;
    float4* out4 = (float4*)out;
#pragma unroll
    for (int mt = 0; mt < 4; ++mt)
#pragma unroll
        for (int nt = 0; nt < 8; ++nt) {
            int oc = nt * 16 + l;
            int px = pxw + mt * 16 + q * 4;
            int gi = (bb * 128 + oc) * 1024 + (px >> 2);
            float4 xv = x4[gi];
            float4 r;
            r.x = gm * acc[mt][nt][0] + xv.x;
            r.y = gm * acc[mt][nt][1] + xv.y;
            r.z = gm * acc[mt][nt][2] + xv.z;
            r.w = gm * acc[mt][nt][3] + xv.w;
            out4[gi] = r;
        }
}

extern "C" void kernel_launch(void* const* d_in, const int* in_sizes, int n_in,
                              void* d_out, int out_size, void* d_ws, size_t ws_size,
                              hipStream_t stream) {
    const float* x  = (const float*)d_in[0];
    const float* wt = (const float*)d_in[1];
    const float* wp = (const float*)d_in[2];
    const float* wg = (const float*)d_in[3];
    const float* wo = (const float*)d_in[4];
    const float* ut = (const float*)d_in[5];
    const float* up = (const float*)d_in[6];
    const float* ug = (const float*)d_in[7];
    const float* uo = (const float*)d_in[8];
    const float* gm = (const float*)d_in[9];
    unsigned short* wsu = (unsigned short*)d_ws;
    float* out = (float*)d_out;

    sn4<<<4, 256, 0, stream>>>(wt, wp, wg, wo, ut, up, ug, uo, wsu);
    convpool_mfma<<<512, 256, 0, stream>>>(x, wsu + U_WN,
                                           wsu + U_TH, wsu + U_PHI, wsu + U_G);
    attn_mfma<<<512, 512, 0, stream>>>(wsu + U_TH, wsu + U_PHI, wsu + U_G, wsu + U_OT);
    outconv_mfma<<<256, 256, 0, stream>>>(wsu + U_OT, wsu + U_WO, x, gm, out);
}

// Round 4
// 154.261 us; speedup vs baseline: 1.0965x; 1.0606x over previous
//
#include <hip/hip_runtime.h>
#include <hip/hip_bf16.h>

// SAGAN self-attention, B=16, C=128, H=W=64. Inputs fp32, output fp32.
// ws layout in ushorts (bf16):
//   U_WN  = 0        : Wn bf16 [96][128] (theta 0..15, phi 16..31, g 32..95)
//   U_WO  = 12288    : Wo bf16 [128][64]
//   U_TH  = 20480    : thetaT bf16 [16 b][4096 s][16 c]
//   U_PHI = 1069056  : phiT   bf16 [16 b][1024 t][16 c]
//   U_G   = 1331200  : g      bf16 [16 b][64 c][1024 t]
//   U_OT  = 2379776  : oT     bf16 [16 b][4096 s][64 c]

#define U_WN  0
#define U_WO  12288
#define U_TH  20480
#define U_PHI 1069056
#define U_G   1331200
#define U_OT  2379776

typedef __attribute__((ext_vector_type(8))) short bf16x8;
typedef __attribute__((ext_vector_type(4))) short s16x4;
typedef __attribute__((ext_vector_type(4))) float f32x4;
typedef __attribute__((ext_vector_type(16))) float f32x16;

__device__ inline unsigned short f2b(float f) {
    union { float f; unsigned u; } v; v.f = f;
    unsigned r = v.u + 0x7FFFu + ((v.u >> 16) & 1u);   // RNE
    return (unsigned short)(r >> 16);
}
__device__ inline float b2f(unsigned short u) {
    union { unsigned u; float f; } v; v.u = ((unsigned)u) << 16; return v.f;
}

// pack two f32 -> one u32 of 2 bf16 (RNE; lo = first arg). s_nop guards
// trans->VALU hazard (producer may be v_exp_f32).
__device__ inline unsigned cvtpk_bf16(float lo, float hi) {
    unsigned r;
    asm("s_nop 0\n\tv_cvt_pk_bf16_f32 %0, %1, %2" : "=v"(r) : "v"(lo), "v"(hi));
    return r;
}
// v_permlane32_swap_b32: exchanges lane halves between a and b
// (mapping verified end-to-end by the passing round-2/3 builds).
__device__ inline void pl32swap(unsigned &a, unsigned &b) {
    asm("s_nop 1\n\tv_permlane32_swap_b32 %0, %1\n\ts_nop 1" : "+v"(a), "+v"(b));
}

// ---------------- Kernel A: spectral norm, emit bf16 weights ----------------
__global__ __launch_bounds__(256) void sn4(
        const float* __restrict__ w0, const float* __restrict__ w1,
        const float* __restrict__ w2, const float* __restrict__ w3,
        const float* __restrict__ u0, const float* __restrict__ u1,
        const float* __restrict__ u2, const float* __restrict__ u3,
        unsigned short* __restrict__ wsu) {
    int wi = blockIdx.x;
    const float* W; const float* u; unsigned short* dst; int on, in_;
    if      (wi == 0) { W = w0; u = u0; dst = wsu;          on = 16;  in_ = 128; }
    else if (wi == 1) { W = w1; u = u1; dst = wsu + 2048;   on = 16;  in_ = 128; }
    else if (wi == 2) { W = w2; u = u2; dst = wsu + 4096;   on = 64;  in_ = 128; }
    else              { W = w3; u = u3; dst = wsu + 12288;  on = 128; in_ = 64;  }
    __shared__ float Wl[8320];    // [on][in_+1], max(128*65, 64*129) = 8320
    __shared__ float ul[128];
    __shared__ float v[128];
    __shared__ float red[256];
    __shared__ float s_inv;
    int tid = threadIdx.x;
    int n = on * in_;
    int stride = in_ + 1;
    int shift = (in_ == 128) ? 7 : 6;
    int mask = in_ - 1;
    for (int i = tid; i < n; i += 256) {
        int o = i >> shift, j = i & mask;
        Wl[o * stride + j] = W[i];
    }
    if (tid < on) ul[tid] = u[tid];
    __syncthreads();
    float vi = 0.f;
    if (tid < in_) {
        for (int o = 0; o < on; ++o) vi += ul[o] * Wl[o * stride + tid];
    }
    red[tid] = (tid < in_) ? vi * vi : 0.f;
    __syncthreads();
    for (int st = 128; st > 0; st >>= 1) {
        if (tid < st) red[tid] += red[tid + st];
        __syncthreads();
    }
    float inv_nv = 1.0f / fmaxf(sqrtf(red[0]), 1e-12f);
    __syncthreads();
    if (tid < in_) v[tid] = vi * inv_nv;
    __syncthreads();
    float ui = 0.f;
    if (tid < on) {
        for (int i = 0; i < in_; ++i) ui += v[i] * Wl[tid * stride + i];
    }
    red[tid] = (tid < on) ? ui * ui : 0.f;
    __syncthreads();
    for (int st = 128; st > 0; st >>= 1) {
        if (tid < st) red[tid] += red[tid + st];
        __syncthreads();
    }
    if (tid == 0) {
        float nsq = red[0];
        float sv = nsq / fmaxf(sqrtf(nsq), 1e-12f);
        s_inv = 1.0f / sv;
    }
    __syncthreads();
    float inv = s_inv;
    for (int e = tid; e < n; e += 256) {
        int o = e >> shift, j = e & mask;
        dst[e] = f2b(Wl[o * stride + j] * inv);
    }
}

// ------- Kernel B: MFMA conv + 2x2 maxpool ----------------------------------
// grid: 512 blocks x 512 threads (8 waves, 16 px each). 2 blocks/CU ->
// 16 waves/CU = 4 waves/SIMD (was 2). Per-wave acc is 6 f32x4 (24 VGPR).
__global__ __launch_bounds__(512, 4) void convpool_mfma(
        const float* __restrict__ x, const unsigned short* __restrict__ wn,
        unsigned short* __restrict__ thetaT, unsigned short* __restrict__ phiT,
        unsigned short* __restrict__ gT) {
    __shared__ unsigned short xT[128 * 136];   // [px][c], stride 136
    __shared__ unsigned short wnl[96 * 136];   // [oc][c], stride 136; reused as poolbuf
    int tid = threadIdx.x;
    int bb = blockIdx.x >> 5, tile = blockIdx.x & 31;
    int px0 = tile << 7;
    for (int i = tid; i < 1536; i += 512) {
        int r = i >> 4, c8 = (i & 15) * 8;
        *(bf16x8*)&wnl[r * 136 + c8] = *(const bf16x8*)&wn[r * 128 + c8];
    }
    const float4* x4 = (const float4*)x;
    {
        int p4 = tid & 31, cg = (tid >> 5) * 4;    // cg 0..60
        for (int k = 0; k < 2; ++k) {
            int cb = k * 64 + cg;
            float4 v0 = x4[(bb * 128 + cb + 0) * 1024 + tile * 32 + p4];
            float4 v1 = x4[(bb * 128 + cb + 1) * 1024 + tile * 32 + p4];
            float4 v2 = x4[(bb * 128 + cb + 2) * 1024 + tile * 32 + p4];
            float4 v3 = x4[(bb * 128 + cb + 3) * 1024 + tile * 32 + p4];
            float a0[4] = {v0.x, v0.y, v0.z, v0.w};
            float a1[4] = {v1.x, v1.y, v1.z, v1.w};
            float a2[4] = {v2.x, v2.y, v2.z, v2.w};
            float a3[4] = {v3.x, v3.y, v3.z, v3.w};
#pragma unroll
            for (int j = 0; j < 4; ++j) {
                union { unsigned w[2]; s16x4 v; } pk;
                pk.w[0] = cvtpk_bf16(a0[j], a1[j]);   // channels cb, cb+1
                pk.w[1] = cvtpk_bf16(a2[j], a3[j]);   // channels cb+2, cb+3
                *(s16x4*)&xT[(p4 * 4 + j) * 136 + cb] = pk.v;
            }
        }
    }
    __syncthreads();
    int lane = tid & 63, wv = tid >> 6;        // wv 0..7
    int q = lane >> 4, l = lane & 15;
    int pxw = wv * 16;
    f32x4 acc[6];
    const f32x4 z4 = {0.f, 0.f, 0.f, 0.f};
#pragma unroll
    for (int nt = 0; nt < 6; ++nt) acc[nt] = z4;
#pragma unroll
    for (int kk = 0; kk < 4; ++kk) {
        bf16x8 a0 = *(const bf16x8*)&xT[(pxw + l) * 136 + kk * 32 + q * 8];
#pragma unroll
        for (int nt = 0; nt < 6; ++nt) {
            bf16x8 bw = *(const bf16x8*)&wnl[(nt * 16 + l) * 136 + kk * 32 + q * 8];
            acc[nt] = __builtin_amdgcn_mfma_f32_16x16x32_bf16(a0, bw, acc[nt], 0, 0, 0);
        }
    }
    // theta (nt=0): thetaT[s][c], c=l
#pragma unroll
    for (int r = 0; r < 4; ++r) {
        int s = px0 + pxw + q * 4 + r;
        thetaT[(bb * 4096 + s) * 16 + l] = f2b(acc[0][r]);
    }
    __syncthreads();   // all waves done reading wnl
    unsigned short* poolbuf = wnl;   // [80 ch][px] stride 132
#pragma unroll
    for (int nt = 1; nt < 6; ++nt) {
        int ch = nt * 16 + l - 16;
#pragma unroll
        for (int r = 0; r < 4; ++r) {
            poolbuf[ch * 132 + pxw + q * 4 + r] = f2b(acc[nt][r]);
        }
    }
    __syncthreads();
    for (int i = tid; i < 2560; i += 512) {
        int tcol = i & 31, ch = i >> 5;
        int base = ch * 132 + tcol * 2;
        float m0 = fmaxf(b2f(poolbuf[base]), b2f(poolbuf[base + 1]));
        float m1 = fmaxf(b2f(poolbuf[base + 64]), b2f(poolbuf[base + 65]));
        float m = fmaxf(m0, m1);
        int t = tile * 32 + tcol;
        if (ch < 16) phiT[(bb * 1024 + t) * 16 + ch] = f2b(m);
        else         gT[(bb * 64 + ch - 16) * 1024 + t] = f2b(m);
    }
}

// ------- Kernel C: MFMA fused attention — t-split, reg-pressure-trimmed -----
// grid: 512 blocks x 512 threads (8 waves = 4 s-groups x 2 t-halves).
// Register trims vs round 3: second S-MFMA deferred until first S-tile's
// exp loop has killed sa (sched_barrier pins it); gf prefetch split into
// two halves. Peak live ~112 VGPR < the 128 cap of launch_bounds(512,4)
// -> no spills at 4 waves/SIMD. setprio(1) around the PV MFMA cluster (T5).
__global__ __launch_bounds__(512, 4) void attn_mfma(
        const unsigned short* __restrict__ thetaT,
        const unsigned short* __restrict__ phiT,
        const unsigned short* __restrict__ gT,
        unsigned short* __restrict__ oT) {
    __shared__ float ldsO[4][2048];   // [sg][c*32 + sl], 32KB
    __shared__ float ldsD[4][32];
    int tid = threadIdx.x;
    // XCD-chunked bijective swizzle (512 = 8 XCD x 64 chunks)
    int kblk = blockIdx.x;
    int vblk = (kblk & 7) * 64 + (kblk >> 3);
    int bb = vblk >> 5, st = vblk & 31;
    int s0 = st << 7;
    int lane = tid & 63, wv = tid >> 6;
    int sg = wv & 3, sp = wv >> 2;
    int sl = lane & 31, hi = lane >> 5;
    int srow = bb * 4096 + s0 + sg * 32 + sl;      // this lane's s (global)
    const unsigned short* phiB = phiT + bb * 16384;    // [1024][16]
    const unsigned short* gB   = gT + bb * 65536;      // [64][1024]
    int tbase = sp << 9;                               // 0 or 512

    // theta B-frag: B[k=c=hi*8+j][col=s=sl], loop-invariant
    bf16x8 bth = *(const bf16x8*)&thetaT[srow * 16 + hi * 8];

    f32x16 z16;
#pragma unroll
    for (int i = 0; i < 16; ++i) z16[i] = 0.f;
    f32x16 acc0 = z16, acc1 = z16;     // O rows c 0..31 / 32..63, col s=sl
    float lp4[4] = {0.f, 0.f, 0.f, 0.f};

    // phi A-frag 1-deep pipeline: A[row=t][k=c=hi*8+j]
    bf16x8 ph0 = *(const bf16x8*)&phiB[(tbase + sl) * 16 + hi * 8];
    bf16x8 ph1 = *(const bf16x8*)&phiB[(tbase + 32 + sl) * 16 + hi * 8];

    for (int tc = 0; tc < 8; ++tc) {
        int t0 = tbase + (tc << 6);
        bf16x8 gf0[4], gf1[4];
        // g A-frags, first half (PV k-groups 0,1)
#pragma unroll
        for (int kt = 0; kt < 2; ++kt) {
            gf0[kt] = *(const bf16x8*)&gB[(sl) * 1024 + t0 + kt * 16 + hi * 8];
            gf1[kt] = *(const bf16x8*)&gB[(32 + sl) * 1024 + t0 + kt * 16 + hi * 8];
        }
        // S^T tile 0: t-block t0+0..31
        f32x16 sa = __builtin_amdgcn_mfma_f32_32x32x16_bf16(ph0, bth, z16, 0, 0, 0);
        unsigned u0[8], u1[8];
#pragma unroll
        for (int i = 0; i < 8; ++i) {
            float e0 = __expf(sa[2 * i]);
            float e1 = __expf(sa[2 * i + 1]);
            lp4[0] += e0; lp4[1] += e1;
            u0[i] = cvtpk_bf16(e0, e1);
        }
        // pin: issue second S-MFMA only after sa is consumed (keeps
        // sa/sb live ranges disjoint -> no spill at the 128-reg cap)
        __builtin_amdgcn_sched_barrier(0);
        f32x16 sb = __builtin_amdgcn_mfma_f32_32x32x16_bf16(ph1, bth, z16, 0, 0, 0);
        // swaps for u0 while sb's MFMA is in flight
        pl32swap(u0[0], u0[2]); pl32swap(u0[1], u0[3]);
        pl32swap(u0[4], u0[6]); pl32swap(u0[5], u0[7]);
        // g second half + next-iter phi prefetch
#pragma unroll
        for (int kt = 2; kt < 4; ++kt) {
            gf0[kt] = *(const bf16x8*)&gB[(sl) * 1024 + t0 + kt * 16 + hi * 8];
            gf1[kt] = *(const bf16x8*)&gB[(32 + sl) * 1024 + t0 + kt * 16 + hi * 8];
        }
        int t0n = tbase + (((tc + 1) & 7) << 6);
        ph0 = *(const bf16x8*)&phiB[(t0n + sl) * 16 + hi * 8];
        ph1 = *(const bf16x8*)&phiB[(t0n + 32 + sl) * 16 + hi * 8];
#pragma unroll
        for (int i = 0; i < 8; ++i) {
            float e2 = __expf(sb[2 * i]);
            float e3 = __expf(sb[2 * i + 1]);
            lp4[2] += e2; lp4[3] += e3;
            u1[i] = cvtpk_bf16(e2, e3);
        }
        pl32swap(u1[0], u1[2]); pl32swap(u1[1], u1[3]);
        pl32swap(u1[4], u1[6]); pl32swap(u1[5], u1[7]);
        // PV: O += g . P  (T5: favor this wave while in the MFMA cluster)
        __builtin_amdgcn_s_setprio(1);
        {
            union { unsigned w[4]; bf16x8 v; } pf = {{u0[0], u0[1], u0[2], u0[3]}};
            acc0 = __builtin_amdgcn_mfma_f32_32x32x16_bf16(gf0[0], pf.v, acc0, 0, 0, 0);
            acc1 = __builtin_amdgcn_mfma_f32_32x32x16_bf16(gf1[0], pf.v, acc1, 0, 0, 0);
        }
        {
            union { unsigned w[4]; bf16x8 v; } pf = {{u0[4], u0[5], u0[6], u0[7]}};
            acc0 = __builtin_amdgcn_mfma_f32_32x32x16_bf16(gf0[1], pf.v, acc0, 0, 0, 0);
            acc1 = __builtin_amdgcn_mfma_f32_32x32x16_bf16(gf1[1], pf.v, acc1, 0, 0, 0);
        }
        {
            union { unsigned w[4]; bf16x8 v; } pf = {{u1[0], u1[1], u1[2], u1[3]}};
            acc0 = __builtin_amdgcn_mfma_f32_32x32x16_bf16(gf0[2], pf.v, acc0, 0, 0, 0);
            acc1 = __builtin_amdgcn_mfma_f32_32x32x16_bf16(gf1[2], pf.v, acc1, 0, 0, 0);
        }
        {
            union { unsigned w[4]; bf16x8 v; } pf = {{u1[4], u1[5], u1[6], u1[7]}};
            acc0 = __builtin_amdgcn_mfma_f32_32x32x16_bf16(gf0[3], pf.v, acc0, 0, 0, 0);
            acc1 = __builtin_amdgcn_mfma_f32_32x32x16_bf16(gf1[3], pf.v, acc1, 0, 0, 0);
        }
        __builtin_amdgcn_s_setprio(0);
    }
    // per-lane partial denominator (s = sl): reduce own 4 + partner half
    float tot = (lp4[0] + lp4[1]) + (lp4[2] + lp4[3]);
    tot += __shfl_xor(tot, 32);

    // cross-split combine via LDS (one barrier). c(i,hi) = (i&3)+8*(i>>2)+4*hi
    if (sp == 1) {
#pragma unroll
        for (int i = 0; i < 16; ++i) {
            int c = (i & 3) + 8 * (i >> 2) + 4 * hi;
            ldsO[sg][c * 32 + sl] = acc0[i];
            ldsO[sg][(32 + c) * 32 + sl] = acc1[i];
        }
        if (hi == 0) ldsD[sg][sl] = tot;
    }
    __syncthreads();
    if (sp == 1) return;
    tot += ldsD[sg][sl];
    float inv = 1.0f / tot;
#pragma unroll
    for (int i = 0; i < 16; ++i) {
        int c = (i & 3) + 8 * (i >> 2) + 4 * hi;
        acc0[i] += ldsO[sg][c * 32 + sl];
        acc1[i] += ldsO[sg][(32 + c) * 32 + sl];
    }
    // pack + store (assembly trick verified rounds 2/3)
    unsigned o0[8], o1[8];
#pragma unroll
    for (int i = 0; i < 8; ++i) {
        o0[i] = cvtpk_bf16(acc0[2 * i] * inv, acc0[2 * i + 1] * inv);
        o1[i] = cvtpk_bf16(acc1[2 * i] * inv, acc1[2 * i + 1] * inv);
    }
    pl32swap(o0[0], o0[2]); pl32swap(o0[1], o0[3]);
    pl32swap(o0[4], o0[6]); pl32swap(o0[5], o0[7]);
    pl32swap(o1[0], o1[2]); pl32swap(o1[1], o1[3]);
    pl32swap(o1[4], o1[6]); pl32swap(o1[5], o1[7]);
    unsigned short* orow = oT + srow * 64;
    {
        union { unsigned w[4]; bf16x8 v; } ow = {{o0[0], o0[1], o0[2], o0[3]}};
        *(bf16x8*)&orow[hi * 8] = ow.v;
    }
    {
        union { unsigned w[4]; bf16x8 v; } ow = {{o0[4], o0[5], o0[6], o0[7]}};
        *(bf16x8*)&orow[16 + hi * 8] = ow.v;
    }
    {
        union { unsigned w[4]; bf16x8 v; } ow = {{o1[0], o1[1], o1[2], o1[3]}};
        *(bf16x8*)&orow[32 + hi * 8] = ow.v;
    }
    {
        union { unsigned w[4]; bf16x8 v; } ow = {{o1[4], o1[5], o1[6], o1[7]}};
        *(bf16x8*)&orow[48 + hi * 8] = ow.v;
    }
}

// ------- Kernel D: out = gamma * (Wo @ o) + x  (MFMA) -----------------------
// grid: 16 b x 64 px-tiles = 1024 blocks x 4 waves, 16 px/wave.
// 4 blocks/CU (LDS 18.4KB) -> 16 waves/CU = 4 waves/SIMD (was 1!).
__global__ __launch_bounds__(256, 4) void outconv_mfma(
        const unsigned short* __restrict__ oT, const unsigned short* __restrict__ wo,
        const float* __restrict__ x, const float* __restrict__ gam,
        float* __restrict__ out) {
    __shared__ unsigned short wol[128 * 72];   // [oc][c] stride 72
    int tid = threadIdx.x;
    int bb = blockIdx.x >> 6, tile = blockIdx.x & 63;
    int lane = tid & 63, wv = tid >> 6;
    int q = lane >> 4, l = lane & 15;
    int pxw = tile * 64 + wv * 16;
    for (int i = tid; i < 1024; i += 256) {
        int r = i >> 3, c8 = (i & 7) * 8;
        *(bf16x8*)&wol[r * 72 + c8] = *(const bf16x8*)&wo[r * 64 + c8];
    }
    // A-frags: 1 m-tile x 2 k-steps
    bf16x8 af[2];
#pragma unroll
    for (int kk = 0; kk < 2; ++kk)
        af[kk] = *(const bf16x8*)&oT[(bb * 4096 + pxw + l) * 64 + kk * 32 + q * 8];
    __syncthreads();
    f32x4 acc[8];
    const f32x4 z4 = {0.f, 0.f, 0.f, 0.f};
#pragma unroll
    for (int nt = 0; nt < 8; ++nt) acc[nt] = z4;
#pragma unroll
    for (int kk = 0; kk < 2; ++kk) {
#pragma unroll
        for (int nt = 0; nt < 8; ++nt) {
            bf16x8 bw = *(const bf16x8*)&wol[(nt * 16 + l) * 72 + kk * 32 + q * 8];
            acc[nt] = __builtin_amdgcn_mfma_f32_16x16x32_bf16(af[kk], bw, acc[nt], 0, 0, 0);
        }
    }
    float gm = gam[0];
    const float4* x4 = (const float4*)x;
    float4* out4 = (float4*)out;
#pragma unroll
    for (int nt = 0; nt < 8; ++nt) {
        int oc = nt * 16 + l;
        int px = pxw + q * 4;
        int gi = (bb * 128 + oc) * 1024 + (px >> 2);
        float4 xv = x4[gi];
        float4 r;
        r.x = gm * acc[nt][0] + xv.x;
        r.y = gm * acc[nt][1] + xv.y;
        r.z = gm * acc[nt][2] + xv.z;
        r.w = gm * acc[nt][3] + xv.w;
        out4[gi] = r;
    }
}

extern "C" void kernel_launch(void* const* d_in, const int* in_sizes, int n_in,
                              void* d_out, int out_size, void* d_ws, size_t ws_size,
                              hipStream_t stream) {
    const float* x  = (const float*)d_in[0];
    const float* wt = (const float*)d_in[1];
    const float* wp = (const float*)d_in[2];
    const float* wg = (const float*)d_in[3];
    const float* wo = (const float*)d_in[4];
    const float* ut = (const float*)d_in[5];
    const float* up = (const float*)d_in[6];
    const float* ug = (const float*)d_in[7];
    const float* uo = (const float*)d_in[8];
    const float* gm = (const float*)d_in[9];
    unsigned short* wsu = (unsigned short*)d_ws;
    float* out = (float*)d_out;

    sn4<<<4, 256, 0, stream>>>(wt, wp, wg, wo, ut, up, ug, uo, wsu);
    convpool_mfma<<<512, 512, 0, stream>>>(x, wsu + U_WN,
                                           wsu + U_TH, wsu + U_PHI, wsu + U_G);
    attn_mfma<<<512, 512, 0, stream>>>(wsu + U_TH, wsu + U_PHI, wsu + U_G, wsu + U_OT);
    outconv_mfma<<<1024, 256, 0, stream>>>(wsu + U_OT, wsu + U_WO, x, gm, out);
}

// Round 5
// 148.094 us; speedup vs baseline: 1.1422x; 1.0416x over previous
//
#include <hip/hip_runtime.h>
#include <hip/hip_bf16.h>

// SAGAN self-attention, B=16, C=128, H=W=64. Inputs fp32, output fp32.
// ws layout in ushorts (bf16):
//   U_WN  = 0        : Wn bf16 [96][128] (theta 0..15, phi 16..31, g 32..95)
//   U_WO  = 12288    : Wo bf16 [128][64]
//   U_TH  = 20480    : thetaT bf16 [16 b][4096 s][16 c]
//   U_PHI = 1069056  : phiT   bf16 [16 b][1024 t][16 c]
//   U_G   = 1331200  : g      bf16 [16 b][64 c][1024 t]
//   (oT eliminated: outconv fused into attn epilogue)

#define U_WN  0
#define U_WO  12288
#define U_TH  20480
#define U_PHI 1069056
#define U_G   1331200

typedef __attribute__((ext_vector_type(8))) short bf16x8;
typedef __attribute__((ext_vector_type(4))) short s16x4;
typedef __attribute__((ext_vector_type(4))) float f32x4;
typedef __attribute__((ext_vector_type(16))) float f32x16;

__device__ inline unsigned short f2b(float f) {
    union { float f; unsigned u; } v; v.f = f;
    unsigned r = v.u + 0x7FFFu + ((v.u >> 16) & 1u);   // RNE
    return (unsigned short)(r >> 16);
}
__device__ inline float b2f(unsigned short u) {
    union { unsigned u; float f; } v; v.u = ((unsigned)u) << 16; return v.f;
}

// pack two f32 -> one u32 of 2 bf16 (RNE; lo = first arg). s_nop guards
// trans->VALU hazard (producer may be v_exp_f32).
__device__ inline unsigned cvtpk_bf16(float lo, float hi) {
    unsigned r;
    asm("s_nop 0\n\tv_cvt_pk_bf16_f32 %0, %1, %2" : "=v"(r) : "v"(lo), "v"(hi));
    return r;
}
// v_permlane32_swap_b32: exchanges lane halves between a and b
// (mapping verified end-to-end by the passing round-2/3/4 builds).
__device__ inline void pl32swap(unsigned &a, unsigned &b) {
    asm("s_nop 1\n\tv_permlane32_swap_b32 %0, %1\n\ts_nop 1" : "+v"(a), "+v"(b));
}

// ---------------- Kernel A: spectral norm, emit bf16 weights ----------------
__global__ __launch_bounds__(256) void sn4(
        const float* __restrict__ w0, const float* __restrict__ w1,
        const float* __restrict__ w2, const float* __restrict__ w3,
        const float* __restrict__ u0, const float* __restrict__ u1,
        const float* __restrict__ u2, const float* __restrict__ u3,
        unsigned short* __restrict__ wsu) {
    int wi = blockIdx.x;
    const float* W; const float* u; unsigned short* dst; int on, in_;
    if      (wi == 0) { W = w0; u = u0; dst = wsu;          on = 16;  in_ = 128; }
    else if (wi == 1) { W = w1; u = u1; dst = wsu + 2048;   on = 16;  in_ = 128; }
    else if (wi == 2) { W = w2; u = u2; dst = wsu + 4096;   on = 64;  in_ = 128; }
    else              { W = w3; u = u3; dst = wsu + 12288;  on = 128; in_ = 64;  }
    __shared__ float Wl[8320];    // [on][in_+1], max(128*65, 64*129) = 8320
    __shared__ float ul[128];
    __shared__ float v[128];
    __shared__ float red[256];
    __shared__ float s_inv;
    int tid = threadIdx.x;
    int n = on * in_;
    int stride = in_ + 1;
    int shift = (in_ == 128) ? 7 : 6;
    int mask = in_ - 1;
    for (int i = tid; i < n; i += 256) {
        int o = i >> shift, j = i & mask;
        Wl[o * stride + j] = W[i];
    }
    if (tid < on) ul[tid] = u[tid];
    __syncthreads();
    float vi = 0.f;
    if (tid < in_) {
        for (int o = 0; o < on; ++o) vi += ul[o] * Wl[o * stride + tid];
    }
    red[tid] = (tid < in_) ? vi * vi : 0.f;
    __syncthreads();
    for (int st = 128; st > 0; st >>= 1) {
        if (tid < st) red[tid] += red[tid + st];
        __syncthreads();
    }
    float inv_nv = 1.0f / fmaxf(sqrtf(red[0]), 1e-12f);
    __syncthreads();
    if (tid < in_) v[tid] = vi * inv_nv;
    __syncthreads();
    float ui = 0.f;
    if (tid < on) {
        for (int i = 0; i < in_; ++i) ui += v[i] * Wl[tid * stride + i];
    }
    red[tid] = (tid < on) ? ui * ui : 0.f;
    __syncthreads();
    for (int st = 128; st > 0; st >>= 1) {
        if (tid < st) red[tid] += red[tid + st];
        __syncthreads();
    }
    if (tid == 0) {
        float nsq = red[0];
        float sv = nsq / fmaxf(sqrtf(nsq), 1e-12f);
        s_inv = 1.0f / sv;
    }
    __syncthreads();
    float inv = s_inv;
    for (int e = tid; e < n; e += 256) {
        int o = e >> shift, j = e & mask;
        dst[e] = f2b(Wl[o * stride + j] * inv);
    }
}

// ------- Kernel B: MFMA conv + 2x2 maxpool (unchanged from round 4) ---------
__global__ __launch_bounds__(512, 4) void convpool_mfma(
        const float* __restrict__ x, const unsigned short* __restrict__ wn,
        unsigned short* __restrict__ thetaT, unsigned short* __restrict__ phiT,
        unsigned short* __restrict__ gT) {
    __shared__ unsigned short xT[128 * 136];   // [px][c], stride 136
    __shared__ unsigned short wnl[96 * 136];   // [oc][c], stride 136; reused as poolbuf
    int tid = threadIdx.x;
    int bb = blockIdx.x >> 5, tile = blockIdx.x & 31;
    int px0 = tile << 7;
    for (int i = tid; i < 1536; i += 512) {
        int r = i >> 4, c8 = (i & 15) * 8;
        *(bf16x8*)&wnl[r * 136 + c8] = *(const bf16x8*)&wn[r * 128 + c8];
    }
    const float4* x4 = (const float4*)x;
    {
        int p4 = tid & 31, cg = (tid >> 5) * 4;    // cg 0..60
        for (int k = 0; k < 2; ++k) {
            int cb = k * 64 + cg;
            float4 v0 = x4[(bb * 128 + cb + 0) * 1024 + tile * 32 + p4];
            float4 v1 = x4[(bb * 128 + cb + 1) * 1024 + tile * 32 + p4];
            float4 v2 = x4[(bb * 128 + cb + 2) * 1024 + tile * 32 + p4];
            float4 v3 = x4[(bb * 128 + cb + 3) * 1024 + tile * 32 + p4];
            float a0[4] = {v0.x, v0.y, v0.z, v0.w};
            float a1[4] = {v1.x, v1.y, v1.z, v1.w};
            float a2[4] = {v2.x, v2.y, v2.z, v2.w};
            float a3[4] = {v3.x, v3.y, v3.z, v3.w};
#pragma unroll
            for (int j = 0; j < 4; ++j) {
                union { unsigned w[2]; s16x4 v; } pk;
                pk.w[0] = cvtpk_bf16(a0[j], a1[j]);   // channels cb, cb+1
                pk.w[1] = cvtpk_bf16(a2[j], a3[j]);   // channels cb+2, cb+3
                *(s16x4*)&xT[(p4 * 4 + j) * 136 + cb] = pk.v;
            }
        }
    }
    __syncthreads();
    int lane = tid & 63, wv = tid >> 6;        // wv 0..7
    int q = lane >> 4, l = lane & 15;
    int pxw = wv * 16;
    f32x4 acc[6];
    const f32x4 z4 = {0.f, 0.f, 0.f, 0.f};
#pragma unroll
    for (int nt = 0; nt < 6; ++nt) acc[nt] = z4;
#pragma unroll
    for (int kk = 0; kk < 4; ++kk) {
        bf16x8 a0 = *(const bf16x8*)&xT[(pxw + l) * 136 + kk * 32 + q * 8];
#pragma unroll
        for (int nt = 0; nt < 6; ++nt) {
            bf16x8 bw = *(const bf16x8*)&wnl[(nt * 16 + l) * 136 + kk * 32 + q * 8];
            acc[nt] = __builtin_amdgcn_mfma_f32_16x16x32_bf16(a0, bw, acc[nt], 0, 0, 0);
        }
    }
    // theta (nt=0): thetaT[s][c], c=l
#pragma unroll
    for (int r = 0; r < 4; ++r) {
        int s = px0 + pxw + q * 4 + r;
        thetaT[(bb * 4096 + s) * 16 + l] = f2b(acc[0][r]);
    }
    __syncthreads();   // all waves done reading wnl
    unsigned short* poolbuf = wnl;   // [80 ch][px] stride 132
#pragma unroll
    for (int nt = 1; nt < 6; ++nt) {
        int ch = nt * 16 + l - 16;
#pragma unroll
        for (int r = 0; r < 4; ++r) {
            poolbuf[ch * 132 + pxw + q * 4 + r] = f2b(acc[nt][r]);
        }
    }
    __syncthreads();
    for (int i = tid; i < 2560; i += 512) {
        int tcol = i & 31, ch = i >> 5;
        int base = ch * 132 + tcol * 2;
        float m0 = fmaxf(b2f(poolbuf[base]), b2f(poolbuf[base + 1]));
        float m1 = fmaxf(b2f(poolbuf[base + 64]), b2f(poolbuf[base + 65]));
        float m = fmaxf(m0, m1);
        int t = tile * 32 + tcol;
        if (ch < 16) phiT[(bb * 1024 + t) * 16 + ch] = f2b(m);
        else         gT[(bb * 64 + ch - 16) * 1024 + t] = f2b(m);
    }
}

// ------- Kernel C: fused attention + output conv + residual -----------------
// grid: 16 b x 64 s-tiles (64 s) = 1024 blocks x 256 threads (4 waves =
// 2 s-groups x 2 t-halves). launch_bounds(256,3): 168-VGPR cap, 12 waves/CU,
// no spills (in-loop live ~140). After the t-split combine, EACH wave holds
// the normalized bf16 O words -- which are exactly the 4 B-frags (K=16
// chunks) for out = Wo @ O. sp=0 computes oc 0..63, sp=1 oc 64..127, writes
// gamma*D + x directly. oT buffer, outconv kernel, and 16.8 MB of traffic
// are eliminated.
__global__ __launch_bounds__(256, 3) void attn_out(
        const unsigned short* __restrict__ thetaT,
        const unsigned short* __restrict__ phiT,
        const unsigned short* __restrict__ gT,
        const unsigned short* __restrict__ wo,
        const float* __restrict__ x, const float* __restrict__ gam,
        float* __restrict__ out) {
    __shared__ float ldsO[2][2][2048];   // [sg][sp][c*32 + sl], 32KB
    __shared__ float ldsD[2][2][32];
    int tid = threadIdx.x;
    // XCD-chunked bijective swizzle (1024 = 8 XCD x 128 chunks)
    int kblk = blockIdx.x;
    int vblk = (kblk & 7) * 128 + (kblk >> 3);
    int bb = vblk >> 6, st = vblk & 63;
    int s0 = st << 6;
    int lane = tid & 63, wv = tid >> 6;
    int sg = wv & 1, sp = wv >> 1;
    int sl = lane & 31, hi = lane >> 5;
    int srow = bb * 4096 + s0 + sg * 32 + sl;      // this lane's s (global)
    const unsigned short* phiB = phiT + bb * 16384;    // [1024][16]
    const unsigned short* gB   = gT + bb * 65536;      // [64][1024]
    int tbase = sp << 9;                               // 0 or 512

    // theta B-frag: B[k=c=hi*8+j][col=s=sl], loop-invariant
    bf16x8 bth = *(const bf16x8*)&thetaT[srow * 16 + hi * 8];

    f32x16 z16;
#pragma unroll
    for (int i = 0; i < 16; ++i) z16[i] = 0.f;
    f32x16 acc0 = z16, acc1 = z16;     // O rows c 0..31 / 32..63, col s=sl
    float lp4[4] = {0.f, 0.f, 0.f, 0.f};

    // phi A-frag 1-deep pipeline: A[row=t][k=c=hi*8+j]
    bf16x8 ph0 = *(const bf16x8*)&phiB[(tbase + sl) * 16 + hi * 8];
    bf16x8 ph1 = *(const bf16x8*)&phiB[(tbase + 32 + sl) * 16 + hi * 8];

    for (int tc = 0; tc < 8; ++tc) {
        int t0 = tbase + (tc << 6);
        bf16x8 gf0[4], gf1[4];
        // g A-frags, first half (PV k-groups 0,1)
#pragma unroll
        for (int kt = 0; kt < 2; ++kt) {
            gf0[kt] = *(const bf16x8*)&gB[(sl) * 1024 + t0 + kt * 16 + hi * 8];
            gf1[kt] = *(const bf16x8*)&gB[(32 + sl) * 1024 + t0 + kt * 16 + hi * 8];
        }
        // S^T tile 0: t-block t0+0..31
        f32x16 sa = __builtin_amdgcn_mfma_f32_32x32x16_bf16(ph0, bth, z16, 0, 0, 0);
        unsigned u0[8], u1[8];
#pragma unroll
        for (int i = 0; i < 8; ++i) {
            float e0 = __expf(sa[2 * i]);
            float e1 = __expf(sa[2 * i + 1]);
            lp4[0] += e0; lp4[1] += e1;
            u0[i] = cvtpk_bf16(e0, e1);
        }
        // pin: issue second S-MFMA only after sa is consumed (keeps
        // sa/sb live ranges disjoint, caps register peak)
        __builtin_amdgcn_sched_barrier(0);
        f32x16 sb = __builtin_amdgcn_mfma_f32_32x32x16_bf16(ph1, bth, z16, 0, 0, 0);
        // swaps for u0 while sb's MFMA is in flight
        pl32swap(u0[0], u0[2]); pl32swap(u0[1], u0[3]);
        pl32swap(u0[4], u0[6]); pl32swap(u0[5], u0[7]);
        // g second half + next-iter phi prefetch
#pragma unroll
        for (int kt = 2; kt < 4; ++kt) {
            gf0[kt] = *(const bf16x8*)&gB[(sl) * 1024 + t0 + kt * 16 + hi * 8];
            gf1[kt] = *(const bf16x8*)&gB[(32 + sl) * 1024 + t0 + kt * 16 + hi * 8];
        }
        int t0n = tbase + (((tc + 1) & 7) << 6);
        ph0 = *(const bf16x8*)&phiB[(t0n + sl) * 16 + hi * 8];
        ph1 = *(const bf16x8*)&phiB[(t0n + 32 + sl) * 16 + hi * 8];
#pragma unroll
        for (int i = 0; i < 8; ++i) {
            float e2 = __expf(sb[2 * i]);
            float e3 = __expf(sb[2 * i + 1]);
            lp4[2] += e2; lp4[3] += e3;
            u1[i] = cvtpk_bf16(e2, e3);
        }
        pl32swap(u1[0], u1[2]); pl32swap(u1[1], u1[3]);
        pl32swap(u1[4], u1[6]); pl32swap(u1[5], u1[7]);
        // PV: O += g . P  (T5: favor this wave in the MFMA cluster)
        __builtin_amdgcn_s_setprio(1);
        {
            union { unsigned w[4]; bf16x8 v; } pf = {{u0[0], u0[1], u0[2], u0[3]}};
            acc0 = __builtin_amdgcn_mfma_f32_32x32x16_bf16(gf0[0], pf.v, acc0, 0, 0, 0);
            acc1 = __builtin_amdgcn_mfma_f32_32x32x16_bf16(gf1[0], pf.v, acc1, 0, 0, 0);
        }
        {
            union { unsigned w[4]; bf16x8 v; } pf = {{u0[4], u0[5], u0[6], u0[7]}};
            acc0 = __builtin_amdgcn_mfma_f32_32x32x16_bf16(gf0[1], pf.v, acc0, 0, 0, 0);
            acc1 = __builtin_amdgcn_mfma_f32_32x32x16_bf16(gf1[1], pf.v, acc1, 0, 0, 0);
        }
        {
            union { unsigned w[4]; bf16x8 v; } pf = {{u1[0], u1[1], u1[2], u1[3]}};
            acc0 = __builtin_amdgcn_mfma_f32_32x32x16_bf16(gf0[2], pf.v, acc0, 0, 0, 0);
            acc1 = __builtin_amdgcn_mfma_f32_32x32x16_bf16(gf1[2], pf.v, acc1, 0, 0, 0);
        }
        {
            union { unsigned w[4]; bf16x8 v; } pf = {{u1[4], u1[5], u1[6], u1[7]}};
            acc0 = __builtin_amdgcn_mfma_f32_32x32x16_bf16(gf0[3], pf.v, acc0, 0, 0, 0);
            acc1 = __builtin_amdgcn_mfma_f32_32x32x16_bf16(gf1[3], pf.v, acc1, 0, 0, 0);
        }
        __builtin_amdgcn_s_setprio(0);
    }
    // per-lane partial denominator (s = sl): reduce own 4 + partner half
    float tot = (lp4[0] + lp4[1]) + (lp4[2] + lp4[3]);
    tot += __shfl_xor(tot, 32);

    // cross-split exchange via LDS: BOTH sp halves write partials, then
    // both combine (each wave ends with the full normalized O words).
#pragma unroll
    for (int i = 0; i < 16; ++i) {
        int c = (i & 3) + 8 * (i >> 2) + 4 * hi;
        ldsO[sg][sp][c * 32 + sl] = acc0[i];
        ldsO[sg][sp][(32 + c) * 32 + sl] = acc1[i];
    }
    if (hi == 0) ldsD[sg][sp][sl] = tot;
    // Wo A-frags for this wave's oc half (L2-hot; issued before the barrier
    // so the loads fly during the LDS exchange). A[row=oc][k=c]:
    // aw[mt][ch] = Wo[(sp*64 + mt*32 + sl)][ch*16 + hi*8 .. +7]
    bf16x8 aw[2][4];
#pragma unroll
    for (int mt = 0; mt < 2; ++mt)
#pragma unroll
        for (int ch = 0; ch < 4; ++ch)
            aw[mt][ch] = *(const bf16x8*)&wo[(sp * 64 + mt * 32 + sl) * 64 + ch * 16 + hi * 8];
    __syncthreads();
    int osp = sp ^ 1;
    tot += ldsD[sg][osp][sl];
    float inv = 1.0f / tot;
#pragma unroll
    for (int i = 0; i < 16; ++i) {
        int c = (i & 3) + 8 * (i >> 2) + 4 * hi;
        acc0[i] += ldsO[sg][osp][c * 32 + sl];
        acc1[i] += ldsO[sg][osp][(32 + c) * 32 + sl];
    }
    // normalized O -> bf16 words (assembly verified rounds 2-4):
    // after swaps, {o0[0..3]} = c hi*8..+7, {o0[4..7]} = c 16+hi*8..+7,
    // {o1[0..3]} = c 32+hi*8..+7, {o1[4..7]} = c 48+hi*8..+7 at col s=sl
    // == the four K=16-chunk B-frags of out = Wo @ O.
    unsigned o0[8], o1[8];
#pragma unroll
    for (int i = 0; i < 8; ++i) {
        o0[i] = cvtpk_bf16(acc0[2 * i] * inv, acc0[2 * i + 1] * inv);
        o1[i] = cvtpk_bf16(acc1[2 * i] * inv, acc1[2 * i + 1] * inv);
    }
    pl32swap(o0[0], o0[2]); pl32swap(o0[1], o0[3]);
    pl32swap(o0[4], o0[6]); pl32swap(o0[5], o0[7]);
    pl32swap(o1[0], o1[2]); pl32swap(o1[1], o1[3]);
    pl32swap(o1[4], o1[6]); pl32swap(o1[5], o1[7]);
    bf16x8 bfr[4];
    {
        union { unsigned w[4]; bf16x8 v; } t;
        t.w[0] = o0[0]; t.w[1] = o0[1]; t.w[2] = o0[2]; t.w[3] = o0[3]; bfr[0] = t.v;
        t.w[0] = o0[4]; t.w[1] = o0[5]; t.w[2] = o0[6]; t.w[3] = o0[7]; bfr[1] = t.v;
        t.w[0] = o1[0]; t.w[1] = o1[1]; t.w[2] = o1[2]; t.w[3] = o1[3]; bfr[2] = t.v;
        t.w[0] = o1[4]; t.w[1] = o1[5]; t.w[2] = o1[6]; t.w[3] = o1[7]; bfr[3] = t.v;
    }
    // out = Wo @ O for this wave's 64 oc rows (2 m-tiles of 32)
    f32x16 d0 = z16, d1 = z16;
#pragma unroll
    for (int ch = 0; ch < 4; ++ch) {
        d0 = __builtin_amdgcn_mfma_f32_32x32x16_bf16(aw[0][ch], bfr[ch], d0, 0, 0, 0);
        d1 = __builtin_amdgcn_mfma_f32_32x32x16_bf16(aw[1][ch], bfr[ch], d1, 0, 0, 0);
    }
    // write gamma*D + x.  D row = oc_local = (i&3)+8*(i>>2)+4*hi, col = s=sl
    float gm = gam[0];
    int scol = s0 + sg * 32 + sl;
#pragma unroll
    for (int i = 0; i < 16; ++i) {
        int r = (i & 3) + 8 * (i >> 2) + 4 * hi;
        int a0 = (bb * 128 + sp * 64 + r) * 4096 + scol;
        int a1 = (bb * 128 + sp * 64 + 32 + r) * 4096 + scol;
        out[a0] = gm * d0[i] + x[a0];
        out[a1] = gm * d1[i] + x[a1];
    }
}

extern "C" void kernel_launch(void* const* d_in, const int* in_sizes, int n_in,
                              void* d_out, int out_size, void* d_ws, size_t ws_size,
                              hipStream_t stream) {
    const float* x  = (const float*)d_in[0];
    const float* wt = (const float*)d_in[1];
    const float* wp = (const float*)d_in[2];
    const float* wg = (const float*)d_in[3];
    const float* wo = (const float*)d_in[4];
    const float* ut = (const float*)d_in[5];
    const float* up = (const float*)d_in[6];
    const float* ug = (const float*)d_in[7];
    const float* uo = (const float*)d_in[8];
    const float* gm = (const float*)d_in[9];
    unsigned short* wsu = (unsigned short*)d_ws;
    float* out = (float*)d_out;

    sn4<<<4, 256, 0, stream>>>(wt, wp, wg, wo, ut, up, ug, uo, wsu);
    convpool_mfma<<<512, 512, 0, stream>>>(x, wsu + U_WN,
                                           wsu + U_TH, wsu + U_PHI, wsu + U_G);
    attn_out<<<1024, 256, 0, stream>>>(wsu + U_TH, wsu + U_PHI, wsu + U_G,
                                       wsu + U_WO, x, gm, out);
}

// Round 6
// 134.009 us; speedup vs baseline: 1.2622x; 1.1051x over previous
//
#include <hip/hip_runtime.h>
#include <hip/hip_bf16.h>

// SAGAN self-attention, B=16, C=128, H=W=64. Inputs fp32, output fp32.
// ws layout in ushorts (bf16):
//   U_WN  = 0        : Wn bf16 [96][128] (theta 0..15, phi 16..31, g 32..95)
//   U_WO  = 12288    : Wo bf16 [128][64]
//   U_TH  = 20480    : thetaT bf16 [16 b][4096 s][16 c]
//   U_PHI = 1069056  : phiT   bf16 [16 b][1024 t][16 c]
//   U_G   = 1331200  : g      bf16 [16 b][64 c][1024 t]

#define U_WN  0
#define U_WO  12288
#define U_TH  20480
#define U_PHI 1069056
#define U_G   1331200

typedef __attribute__((ext_vector_type(8))) short bf16x8;
typedef __attribute__((ext_vector_type(4))) short s16x4;
typedef __attribute__((ext_vector_type(4))) float f32x4;
typedef __attribute__((ext_vector_type(16))) float f32x16;

__device__ inline unsigned short f2b(float f) {
    union { float f; unsigned u; } v; v.f = f;
    unsigned r = v.u + 0x7FFFu + ((v.u >> 16) & 1u);   // RNE
    return (unsigned short)(r >> 16);
}
__device__ inline float b2f(unsigned short u) {
    union { unsigned u; float f; } v; v.u = ((unsigned)u) << 16; return v.f;
}

// pack two f32 -> one u32 of 2 bf16 (RNE; lo = first arg). s_nop guards
// trans->VALU hazard (producer may be v_exp_f32).
__device__ inline unsigned cvtpk_bf16(float lo, float hi) {
    unsigned r;
    asm("s_nop 0\n\tv_cvt_pk_bf16_f32 %0, %1, %2" : "=v"(r) : "v"(lo), "v"(hi));
    return r;
}
// v_permlane32_swap_b32: exchanges lane halves between a and b
// (mapping verified end-to-end by the passing round-2..5 builds).
__device__ inline void pl32swap(unsigned &a, unsigned &b) {
    asm("s_nop 1\n\tv_permlane32_swap_b32 %0, %1\n\ts_nop 1" : "+v"(a), "+v"(b));
}

// ---------------- Kernel A: spectral norm, emit bf16 weights ----------------
__global__ __launch_bounds__(256) void sn4(
        const float* __restrict__ w0, const float* __restrict__ w1,
        const float* __restrict__ w2, const float* __restrict__ w3,
        const float* __restrict__ u0, const float* __restrict__ u1,
        const float* __restrict__ u2, const float* __restrict__ u3,
        unsigned short* __restrict__ wsu) {
    int wi = blockIdx.x;
    const float* W; const float* u; unsigned short* dst; int on, in_;
    if      (wi == 0) { W = w0; u = u0; dst = wsu;          on = 16;  in_ = 128; }
    else if (wi == 1) { W = w1; u = u1; dst = wsu + 2048;   on = 16;  in_ = 128; }
    else if (wi == 2) { W = w2; u = u2; dst = wsu + 4096;   on = 64;  in_ = 128; }
    else              { W = w3; u = u3; dst = wsu + 12288;  on = 128; in_ = 64;  }
    __shared__ float Wl[8320];    // [on][in_+1], max(128*65, 64*129) = 8320
    __shared__ float ul[128];
    __shared__ float v[128];
    __shared__ float red[256];
    __shared__ float s_inv;
    int tid = threadIdx.x;
    int n = on * in_;
    int stride = in_ + 1;
    int shift = (in_ == 128) ? 7 : 6;
    int mask = in_ - 1;
    for (int i = tid; i < n; i += 256) {
        int o = i >> shift, j = i & mask;
        Wl[o * stride + j] = W[i];
    }
    if (tid < on) ul[tid] = u[tid];
    __syncthreads();
    float vi = 0.f;
    if (tid < in_) {
        for (int o = 0; o < on; ++o) vi += ul[o] * Wl[o * stride + tid];
    }
    red[tid] = (tid < in_) ? vi * vi : 0.f;
    __syncthreads();
    for (int st = 128; st > 0; st >>= 1) {
        if (tid < st) red[tid] += red[tid + st];
        __syncthreads();
    }
    float inv_nv = 1.0f / fmaxf(sqrtf(red[0]), 1e-12f);
    __syncthreads();
    if (tid < in_) v[tid] = vi * inv_nv;
    __syncthreads();
    float ui = 0.f;
    if (tid < on) {
        for (int i = 0; i < in_; ++i) ui += v[i] * Wl[tid * stride + i];
    }
    red[tid] = (tid < on) ? ui * ui : 0.f;
    __syncthreads();
    for (int st = 128; st > 0; st >>= 1) {
        if (tid < st) red[tid] += red[tid + st];
        __syncthreads();
    }
    if (tid == 0) {
        float nsq = red[0];
        float sv = nsq / fmaxf(sqrtf(nsq), 1e-12f);
        s_inv = 1.0f / sv;
    }
    __syncthreads();
    float inv = s_inv;
    for (int e = tid; e < n; e += 256) {
        int o = e >> shift, j = e & mask;
        dst[e] = f2b(Wl[o * stride + j] * inv);
    }
}

// ------- Kernel B: MFMA conv + 2x2 maxpool (unchanged from round 4) ---------
__global__ __launch_bounds__(512, 4) void convpool_mfma(
        const float* __restrict__ x, const unsigned short* __restrict__ wn,
        unsigned short* __restrict__ thetaT, unsigned short* __restrict__ phiT,
        unsigned short* __restrict__ gT) {
    __shared__ unsigned short xT[128 * 136];   // [px][c], stride 136
    __shared__ unsigned short wnl[96 * 136];   // [oc][c], stride 136; reused as poolbuf
    int tid = threadIdx.x;
    int bb = blockIdx.x >> 5, tile = blockIdx.x & 31;
    int px0 = tile << 7;
    for (int i = tid; i < 1536; i += 512) {
        int r = i >> 4, c8 = (i & 15) * 8;
        *(bf16x8*)&wnl[r * 136 + c8] = *(const bf16x8*)&wn[r * 128 + c8];
    }
    const float4* x4 = (const float4*)x;
    {
        int p4 = tid & 31, cg = (tid >> 5) * 4;    // cg 0..60
        for (int k = 0; k < 2; ++k) {
            int cb = k * 64 + cg;
            float4 v0 = x4[(bb * 128 + cb + 0) * 1024 + tile * 32 + p4];
            float4 v1 = x4[(bb * 128 + cb + 1) * 1024 + tile * 32 + p4];
            float4 v2 = x4[(bb * 128 + cb + 2) * 1024 + tile * 32 + p4];
            float4 v3 = x4[(bb * 128 + cb + 3) * 1024 + tile * 32 + p4];
            float a0[4] = {v0.x, v0.y, v0.z, v0.w};
            float a1[4] = {v1.x, v1.y, v1.z, v1.w};
            float a2[4] = {v2.x, v2.y, v2.z, v2.w};
            float a3[4] = {v3.x, v3.y, v3.z, v3.w};
#pragma unroll
            for (int j = 0; j < 4; ++j) {
                union { unsigned w[2]; s16x4 v; } pk;
                pk.w[0] = cvtpk_bf16(a0[j], a1[j]);   // channels cb, cb+1
                pk.w[1] = cvtpk_bf16(a2[j], a3[j]);   // channels cb+2, cb+3
                *(s16x4*)&xT[(p4 * 4 + j) * 136 + cb] = pk.v;
            }
        }
    }
    __syncthreads();
    int lane = tid & 63, wv = tid >> 6;        // wv 0..7
    int q = lane >> 4, l = lane & 15;
    int pxw = wv * 16;
    f32x4 acc[6];
    const f32x4 z4 = {0.f, 0.f, 0.f, 0.f};
#pragma unroll
    for (int nt = 0; nt < 6; ++nt) acc[nt] = z4;
#pragma unroll
    for (int kk = 0; kk < 4; ++kk) {
        bf16x8 a0 = *(const bf16x8*)&xT[(pxw + l) * 136 + kk * 32 + q * 8];
#pragma unroll
        for (int nt = 0; nt < 6; ++nt) {
            bf16x8 bw = *(const bf16x8*)&wnl[(nt * 16 + l) * 136 + kk * 32 + q * 8];
            acc[nt] = __builtin_amdgcn_mfma_f32_16x16x32_bf16(a0, bw, acc[nt], 0, 0, 0);
        }
    }
    // theta (nt=0): thetaT[s][c], c=l
#pragma unroll
    for (int r = 0; r < 4; ++r) {
        int s = px0 + pxw + q * 4 + r;
        thetaT[(bb * 4096 + s) * 16 + l] = f2b(acc[0][r]);
    }
    __syncthreads();   // all waves done reading wnl
    unsigned short* poolbuf = wnl;   // [80 ch][px] stride 132
#pragma unroll
    for (int nt = 1; nt < 6; ++nt) {
        int ch = nt * 16 + l - 16;
#pragma unroll
        for (int r = 0; r < 4; ++r) {
            poolbuf[ch * 132 + pxw + q * 4 + r] = f2b(acc[nt][r]);
        }
    }
    __syncthreads();
    for (int i = tid; i < 2560; i += 512) {
        int tcol = i & 31, ch = i >> 5;
        int base = ch * 132 + tcol * 2;
        float m0 = fmaxf(b2f(poolbuf[base]), b2f(poolbuf[base + 1]));
        float m1 = fmaxf(b2f(poolbuf[base + 64]), b2f(poolbuf[base + 65]));
        float m = fmaxf(m0, m1);
        int t = tile * 32 + tcol;
        if (ch < 16) phiT[(bb * 1024 + t) * 16 + ch] = f2b(m);
        else         gT[(bb * 64 + ch - 16) * 1024 + t] = f2b(m);
    }
}

// ------- Kernel C: fused attention + output conv + residual -----------------
// grid: 16 b x 64 s-tiles (64 s) = 1024 blocks x 256 threads (4 waves =
// 2 s-groups x 2 t-halves). launch_bounds(256,4): 128-reg cap -> 4 waves/SIMD
// (16 waves/CU, was 3/12 at (256,3)). g is cooperatively staged in LDS,
// double-buffered 16KB/iter, XOR-swizzled (off ^= (row&7)<<3 shorts) on both
// write and read so PV's ds_read_b128 avoids the 32-way row-column conflict.
// Each thread loads next chunk at iter top (full compute phase covers L2
// latency), writes LDS at iter end, 1 barrier/iter. The 32KB g buffer is
// reused as the cross-split combine buffer after the loop.
__global__ __launch_bounds__(256, 4) void attn_out(
        const unsigned short* __restrict__ thetaT,
        const unsigned short* __restrict__ phiT,
        const unsigned short* __restrict__ gT,
        const unsigned short* __restrict__ wo,
        const float* __restrict__ x, const float* __restrict__ gam,
        float* __restrict__ out) {
    __shared__ unsigned short gl[2][2][4096];  // [dbuf][t-half][64c x 64t swz] 32KB
    __shared__ float ldsD[2][2][32];
    float* ldsOf = (float*)&gl[0][0][0];       // combine view (post-loop reuse)
    int tid = threadIdx.x;
    // XCD-chunked bijective swizzle (1024 = 8 XCD x 128 chunks)
    int kblk = blockIdx.x;
    int vblk = (kblk & 7) * 128 + (kblk >> 3);
    int bb = vblk >> 6, st = vblk & 63;
    int s0 = st << 6;
    int lane = tid & 63, wv = tid >> 6;
    int sg = wv & 1, sp = wv >> 1;
    int sl = lane & 31, hi = lane >> 5;
    int srow = bb * 4096 + s0 + sg * 32 + sl;      // this lane's s (global)
    const unsigned short* phiB = phiT + bb * 16384;    // [1024][16]
    const unsigned short* gB   = gT + bb * 65536;      // [64][1024]
    int tbase = sp << 9;                               // 0 or 512

    // staging role: 128 threads per t-half (waves 0,1 -> half 0 = their own)
    int sidx = tid & 127, shalf = tid >> 7;
    int src_c = sidx >> 1, spos = sidx & 1;
    const unsigned short* gsrc = gB + src_c * 1024 + shalf * 512 + spos * 32;
    unsigned short* glw = &gl[0][0][0];
    int wrow = src_c * 64;
    int wsw  = (src_c & 7) << 3;
    int wo_0 = (spos * 32 + 0)  ^ wsw, wo_1 = (spos * 32 + 8)  ^ wsw;
    int wo_2 = (spos * 32 + 16) ^ wsw, wo_3 = (spos * 32 + 24) ^ wsw;

    // theta B-frag: B[k=c=hi*8+j][col=s=sl], loop-invariant
    bf16x8 bth = *(const bf16x8*)&thetaT[srow * 16 + hi * 8];

    // prologue: stage g chunk tc=0 (both halves)
    {
        bf16x8 r0 = *(const bf16x8*)&gsrc[0];
        bf16x8 r1 = *(const bf16x8*)&gsrc[8];
        bf16x8 r2 = *(const bf16x8*)&gsrc[16];
        bf16x8 r3 = *(const bf16x8*)&gsrc[24];
        unsigned short* d = &glw[shalf * 4096 + wrow];
        *(bf16x8*)&d[wo_0] = r0; *(bf16x8*)&d[wo_1] = r1;
        *(bf16x8*)&d[wo_2] = r2; *(bf16x8*)&d[wo_3] = r3;
    }

    f32x16 z16;
#pragma unroll
    for (int i = 0; i < 16; ++i) z16[i] = 0.f;
    f32x16 acc0 = z16, acc1 = z16;     // O rows c 0..31 / 32..63, col s=sl
    float lp4[4] = {0.f, 0.f, 0.f, 0.f};

    // phi A-frag 1-deep pipeline: A[row=t][k=c=hi*8+j]
    bf16x8 ph0 = *(const bf16x8*)&phiB[(tbase + sl) * 16 + hi * 8];
    bf16x8 ph1 = *(const bf16x8*)&phiB[(tbase + 32 + sl) * 16 + hi * 8];
    __syncthreads();   // g chunk 0 staged

    int rsw = (sl & 7) << 3;
    for (int tc = 0; tc < 8; ++tc) {
        int buf = tc & 1;
        // issue next g-chunk loads early (one full compute phase of cover)
        bf16x8 r0, r1, r2, r3;
        if (tc < 7) {
            const unsigned short* gs = gsrc + (tc + 1) * 64;
            r0 = *(const bf16x8*)&gs[0];
            r1 = *(const bf16x8*)&gs[8];
            r2 = *(const bf16x8*)&gs[16];
            r3 = *(const bf16x8*)&gs[24];
        }
        // S^T tile 0: t-block t0+0..31
        f32x16 sa = __builtin_amdgcn_mfma_f32_32x32x16_bf16(ph0, bth, z16, 0, 0, 0);
        unsigned u0[8], u1[8];
#pragma unroll
        for (int i = 0; i < 8; ++i) {
            float e0 = __expf(sa[2 * i]);
            float e1 = __expf(sa[2 * i + 1]);
            lp4[0] += e0; lp4[1] += e1;
            u0[i] = cvtpk_bf16(e0, e1);
        }
        // pin: issue second S-MFMA only after sa is consumed (disjoint
        // sa/sb live ranges -> lower register peak)
        __builtin_amdgcn_sched_barrier(0);
        f32x16 sb = __builtin_amdgcn_mfma_f32_32x32x16_bf16(ph1, bth, z16, 0, 0, 0);
        // swaps for u0 while sb's MFMA is in flight
        pl32swap(u0[0], u0[2]); pl32swap(u0[1], u0[3]);
        pl32swap(u0[4], u0[6]); pl32swap(u0[5], u0[7]);
        // next-iter phi prefetch
        int t0n = tbase + (((tc + 1) & 7) << 6);
        ph0 = *(const bf16x8*)&phiB[(t0n + sl) * 16 + hi * 8];
        ph1 = *(const bf16x8*)&phiB[(t0n + 32 + sl) * 16 + hi * 8];
#pragma unroll
        for (int i = 0; i < 8; ++i) {
            float e2 = __expf(sb[2 * i]);
            float e3 = __expf(sb[2 * i + 1]);
            lp4[2] += e2; lp4[3] += e3;
            u1[i] = cvtpk_bf16(e2, e3);
        }
        pl32swap(u1[0], u1[2]); pl32swap(u1[1], u1[3]);
        pl32swap(u1[4], u1[6]); pl32swap(u1[5], u1[7]);
        // PV from LDS (swizzled ds_read_b128); T5 setprio around the cluster
        const unsigned short* glr = &glw[(buf * 2 + sp) * 4096];
        __builtin_amdgcn_s_setprio(1);
        {
            int co = (0 * 16 + hi * 8) ^ rsw;
            bf16x8 gf0 = *(const bf16x8*)&glr[sl * 64 + co];
            bf16x8 gf1 = *(const bf16x8*)&glr[(32 + sl) * 64 + co];
            union { unsigned w[4]; bf16x8 v; } pf = {{u0[0], u0[1], u0[2], u0[3]}};
            acc0 = __builtin_amdgcn_mfma_f32_32x32x16_bf16(gf0, pf.v, acc0, 0, 0, 0);
            acc1 = __builtin_amdgcn_mfma_f32_32x32x16_bf16(gf1, pf.v, acc1, 0, 0, 0);
        }
        {
            int co = (1 * 16 + hi * 8) ^ rsw;
            bf16x8 gf0 = *(const bf16x8*)&glr[sl * 64 + co];
            bf16x8 gf1 = *(const bf16x8*)&glr[(32 + sl) * 64 + co];
            union { unsigned w[4]; bf16x8 v; } pf = {{u0[4], u0[5], u0[6], u0[7]}};
            acc0 = __builtin_amdgcn_mfma_f32_32x32x16_bf16(gf0, pf.v, acc0, 0, 0, 0);
            acc1 = __builtin_amdgcn_mfma_f32_32x32x16_bf16(gf1, pf.v, acc1, 0, 0, 0);
        }
        {
            int co = (2 * 16 + hi * 8) ^ rsw;
            bf16x8 gf0 = *(const bf16x8*)&glr[sl * 64 + co];
            bf16x8 gf1 = *(const bf16x8*)&glr[(32 + sl) * 64 + co];
            union { unsigned w[4]; bf16x8 v; } pf = {{u1[0], u1[1], u1[2], u1[3]}};
            acc0 = __builtin_amdgcn_mfma_f32_32x32x16_bf16(gf0, pf.v, acc0, 0, 0, 0);
            acc1 = __builtin_amdgcn_mfma_f32_32x32x16_bf16(gf1, pf.v, acc1, 0, 0, 0);
        }
        {
            int co = (3 * 16 + hi * 8) ^ rsw;
            bf16x8 gf0 = *(const bf16x8*)&glr[sl * 64 + co];
            bf16x8 gf1 = *(const bf16x8*)&glr[(32 + sl) * 64 + co];
            union { unsigned w[4]; bf16x8 v; } pf = {{u1[4], u1[5], u1[6], u1[7]}};
            acc0 = __builtin_amdgcn_mfma_f32_32x32x16_bf16(gf0, pf.v, acc0, 0, 0, 0);
            acc1 = __builtin_amdgcn_mfma_f32_32x32x16_bf16(gf1, pf.v, acc1, 0, 0, 0);
        }
        __builtin_amdgcn_s_setprio(0);
        // commit next chunk to the other buffer; barrier gates both
        // visibility (next iter reads it) and reuse (this buf re-written
        // only after all waves passed)
        if (tc < 7) {
            unsigned short* d = &glw[((buf ^ 1) * 2 + shalf) * 4096 + wrow];
            *(bf16x8*)&d[wo_0] = r0; *(bf16x8*)&d[wo_1] = r1;
            *(bf16x8*)&d[wo_2] = r2; *(bf16x8*)&d[wo_3] = r3;
            __syncthreads();
        }
    }
    __syncthreads();   // all PV reads done before gl is reused as ldsOf

    // per-lane partial denominator (s = sl): reduce own 4 + partner half
    float tot = (lp4[0] + lp4[1]) + (lp4[2] + lp4[3]);
    tot += __shfl_xor(tot, 32);

    // cross-split exchange via LDS: both sp halves write partials, both
    // combine (each wave ends with the full normalized O words).
#pragma unroll
    for (int i = 0; i < 16; ++i) {
        int c = (i & 3) + 8 * (i >> 2) + 4 * hi;
        ldsOf[(sg * 2 + sp) * 2048 + c * 32 + sl] = acc0[i];
        ldsOf[(sg * 2 + sp) * 2048 + (32 + c) * 32 + sl] = acc1[i];
    }
    if (hi == 0) ldsD[sg][sp][sl] = tot;
    // Wo A-frags for this wave's oc half (issued before the barrier so the
    // loads fly during the LDS exchange). aw[mt][ch] = Wo[sp*64+mt*32+sl][ch*16+hi*8..]
    bf16x8 aw[2][4];
#pragma unroll
    for (int mt = 0; mt < 2; ++mt)
#pragma unroll
        for (int ch = 0; ch < 4; ++ch)
            aw[mt][ch] = *(const bf16x8*)&wo[(sp * 64 + mt * 32 + sl) * 64 + ch * 16 + hi * 8];
    __syncthreads();
    int osp = sp ^ 1;
    tot += ldsD[sg][osp][sl];
    float inv = 1.0f / tot;
#pragma unroll
    for (int i = 0; i < 16; ++i) {
        int c = (i & 3) + 8 * (i >> 2) + 4 * hi;
        acc0[i] += ldsOf[(sg * 2 + osp) * 2048 + c * 32 + sl];
        acc1[i] += ldsOf[(sg * 2 + osp) * 2048 + (32 + c) * 32 + sl];
    }
    // normalized O -> bf16 B-frags of out = Wo @ O (verified rounds 2-5)
    unsigned o0[8], o1[8];
#pragma unroll
    for (int i = 0; i < 8; ++i) {
        o0[i] = cvtpk_bf16(acc0[2 * i] * inv, acc0[2 * i + 1] * inv);
        o1[i] = cvtpk_bf16(acc1[2 * i] * inv, acc1[2 * i + 1] * inv);
    }
    pl32swap(o0[0], o0[2]); pl32swap(o0[1], o0[3]);
    pl32swap(o0[4], o0[6]); pl32swap(o0[5], o0[7]);
    pl32swap(o1[0], o1[2]); pl32swap(o1[1], o1[3]);
    pl32swap(o1[4], o1[6]); pl32swap(o1[5], o1[7]);
    bf16x8 bfr[4];
    {
        union { unsigned w[4]; bf16x8 v; } t;
        t.w[0] = o0[0]; t.w[1] = o0[1]; t.w[2] = o0[2]; t.w[3] = o0[3]; bfr[0] = t.v;
        t.w[0] = o0[4]; t.w[1] = o0[5]; t.w[2] = o0[6]; t.w[3] = o0[7]; bfr[1] = t.v;
        t.w[0] = o1[0]; t.w[1] = o1[1]; t.w[2] = o1[2]; t.w[3] = o1[3]; bfr[2] = t.v;
        t.w[0] = o1[4]; t.w[1] = o1[5]; t.w[2] = o1[6]; t.w[3] = o1[7]; bfr[3] = t.v;
    }
    // out = Wo @ O for this wave's 64 oc rows (2 m-tiles of 32)
    f32x16 d0 = z16, d1 = z16;
#pragma unroll
    for (int ch = 0; ch < 4; ++ch) {
        d0 = __builtin_amdgcn_mfma_f32_32x32x16_bf16(aw[0][ch], bfr[ch], d0, 0, 0, 0);
        d1 = __builtin_amdgcn_mfma_f32_32x32x16_bf16(aw[1][ch], bfr[ch], d1, 0, 0, 0);
    }
    // write gamma*D + x.  D row = oc_local = (i&3)+8*(i>>2)+4*hi, col = s=sl
    float gm = gam[0];
    int scol = s0 + sg * 32 + sl;
#pragma unroll
    for (int i = 0; i < 16; ++i) {
        int r = (i & 3) + 8 * (i >> 2) + 4 * hi;
        int a0 = (bb * 128 + sp * 64 + r) * 4096 + scol;
        int a1 = (bb * 128 + sp * 64 + 32 + r) * 4096 + scol;
        out[a0] = gm * d0[i] + x[a0];
        out[a1] = gm * d1[i] + x[a1];
    }
}

extern "C" void kernel_launch(void* const* d_in, const int* in_sizes, int n_in,
                              void* d_out, int out_size, void* d_ws, size_t ws_size,
                              hipStream_t stream) {
    const float* x  = (const float*)d_in[0];
    const float* wt = (const float*)d_in[1];
    const float* wp = (const float*)d_in[2];
    const float* wg = (const float*)d_in[3];
    const float* wo = (const float*)d_in[4];
    const float* ut = (const float*)d_in[5];
    const float* up = (const float*)d_in[6];
    const float* ug = (const float*)d_in[7];
    const float* uo = (const float*)d_in[8];
    const float* gm = (const float*)d_in[9];
    unsigned short* wsu = (unsigned short*)d_ws;
    float* out = (float*)d_out;

    sn4<<<4, 256, 0, stream>>>(wt, wp, wg, wo, ut, up, ug, uo, wsu);
    convpool_mfma<<<512, 512, 0, stream>>>(x, wsu + U_WN,
                                           wsu + U_TH, wsu + U_PHI, wsu + U_G);
    attn_out<<<1024, 256, 0, stream>>>(wsu + U_TH, wsu + U_PHI, wsu + U_G,
                                       wsu + U_WO, x, gm, out);
}

// Round 7
// 131.705 us; speedup vs baseline: 1.2843x; 1.0175x over previous
//
#include <hip/hip_runtime.h>
#include <hip/hip_bf16.h>

// SAGAN self-attention, B=16, C=128, H=W=64. Inputs fp32, output fp32.
// ws layout in ushorts (bf16):
//   U_WN  = 0        : Wn bf16 [96][128] (theta 0..15, phi 16..31, g 32..95)
//   U_WO  = 12288    : Wo bf16 [128][64]
//   U_TH  = 20480    : thetaT bf16 [16 b][4096 s][16 c]
//   U_PHI = 1069056  : phiT   bf16 [16 b][1024 t][16 c]
//   U_G   = 1331200  : g      bf16 [16 b][64 c][1024 t]

#define U_WN  0
#define U_WO  12288
#define U_TH  20480
#define U_PHI 1069056
#define U_G   1331200

typedef __attribute__((ext_vector_type(8))) short bf16x8;
typedef __attribute__((ext_vector_type(4))) short s16x4;
typedef __attribute__((ext_vector_type(4))) float f32x4;
typedef __attribute__((ext_vector_type(16))) float f32x16;

__device__ inline unsigned short f2b(float f) {
    union { float f; unsigned u; } v; v.f = f;
    unsigned r = v.u + 0x7FFFu + ((v.u >> 16) & 1u);   // RNE
    return (unsigned short)(r >> 16);
}
__device__ inline float b2f(unsigned short u) {
    union { unsigned u; float f; } v; v.u = ((unsigned)u) << 16; return v.f;
}

// pack two f32 -> one u32 of 2 bf16 (RNE; lo = first arg). s_nop guards
// trans->VALU hazard (producer may be v_exp_f32).
__device__ inline unsigned cvtpk_bf16(float lo, float hi) {
    unsigned r;
    asm("s_nop 0\n\tv_cvt_pk_bf16_f32 %0, %1, %2" : "=v"(r) : "v"(lo), "v"(hi));
    return r;
}
// v_permlane32_swap_b32: exchanges lane halves between a and b
// (mapping verified end-to-end by the passing round-2..6 builds).
__device__ inline void pl32swap(unsigned &a, unsigned &b) {
    asm("s_nop 1\n\tv_permlane32_swap_b32 %0, %1\n\ts_nop 1" : "+v"(a), "+v"(b));
}
// async global->LDS DMA, 16B per lane: LDS dest = wave-uniform base +
// lane*16; global source is per-lane (pre-swizzled).
__device__ inline void gload_lds16(const unsigned short* g, unsigned short* l) {
    __builtin_amdgcn_global_load_lds(
        (const __attribute__((address_space(1))) unsigned int*)g,
        (__attribute__((address_space(3))) unsigned int*)l, 16, 0, 0);
}

// ---------------- Kernel A: spectral norm, emit bf16 weights ----------------
__global__ __launch_bounds__(256) void sn4(
        const float* __restrict__ w0, const float* __restrict__ w1,
        const float* __restrict__ w2, const float* __restrict__ w3,
        const float* __restrict__ u0, const float* __restrict__ u1,
        const float* __restrict__ u2, const float* __restrict__ u3,
        unsigned short* __restrict__ wsu) {
    int wi = blockIdx.x;
    const float* W; const float* u; unsigned short* dst; int on, in_;
    if      (wi == 0) { W = w0; u = u0; dst = wsu;          on = 16;  in_ = 128; }
    else if (wi == 1) { W = w1; u = u1; dst = wsu + 2048;   on = 16;  in_ = 128; }
    else if (wi == 2) { W = w2; u = u2; dst = wsu + 4096;   on = 64;  in_ = 128; }
    else              { W = w3; u = u3; dst = wsu + 12288;  on = 128; in_ = 64;  }
    __shared__ float Wl[8320];    // [on][in_+1], max(128*65, 64*129) = 8320
    __shared__ float ul[128];
    __shared__ float v[128];
    __shared__ float red[256];
    __shared__ float s_inv;
    int tid = threadIdx.x;
    int n = on * in_;
    int stride = in_ + 1;
    int shift = (in_ == 128) ? 7 : 6;
    int mask = in_ - 1;
    for (int i = tid; i < n; i += 256) {
        int o = i >> shift, j = i & mask;
        Wl[o * stride + j] = W[i];
    }
    if (tid < on) ul[tid] = u[tid];
    __syncthreads();
    float vi = 0.f;
    if (tid < in_) {
        for (int o = 0; o < on; ++o) vi += ul[o] * Wl[o * stride + tid];
    }
    red[tid] = (tid < in_) ? vi * vi : 0.f;
    __syncthreads();
    for (int st = 128; st > 0; st >>= 1) {
        if (tid < st) red[tid] += red[tid + st];
        __syncthreads();
    }
    float inv_nv = 1.0f / fmaxf(sqrtf(red[0]), 1e-12f);
    __syncthreads();
    if (tid < in_) v[tid] = vi * inv_nv;
    __syncthreads();
    float ui = 0.f;
    if (tid < on) {
        for (int i = 0; i < in_; ++i) ui += v[i] * Wl[tid * stride + i];
    }
    red[tid] = (tid < on) ? ui * ui : 0.f;
    __syncthreads();
    for (int st = 128; st > 0; st >>= 1) {
        if (tid < st) red[tid] += red[tid + st];
        __syncthreads();
    }
    if (tid == 0) {
        float nsq = red[0];
        float sv = nsq / fmaxf(sqrtf(nsq), 1e-12f);
        s_inv = 1.0f / sv;
    }
    __syncthreads();
    float inv = s_inv;
    for (int e = tid; e < n; e += 256) {
        int o = e >> shift, j = e & mask;
        dst[e] = f2b(Wl[o * stride + j] * inv);
    }
}

// ------- Kernel B: MFMA conv + 2x2 maxpool (unchanged from round 4) ---------
__global__ __launch_bounds__(512, 4) void convpool_mfma(
        const float* __restrict__ x, const unsigned short* __restrict__ wn,
        unsigned short* __restrict__ thetaT, unsigned short* __restrict__ phiT,
        unsigned short* __restrict__ gT) {
    __shared__ unsigned short xT[128 * 136];   // [px][c], stride 136
    __shared__ unsigned short wnl[96 * 136];   // [oc][c], stride 136; reused as poolbuf
    int tid = threadIdx.x;
    int bb = blockIdx.x >> 5, tile = blockIdx.x & 31;
    int px0 = tile << 7;
    for (int i = tid; i < 1536; i += 512) {
        int r = i >> 4, c8 = (i & 15) * 8;
        *(bf16x8*)&wnl[r * 136 + c8] = *(const bf16x8*)&wn[r * 128 + c8];
    }
    const float4* x4 = (const float4*)x;
    {
        int p4 = tid & 31, cg = (tid >> 5) * 4;    // cg 0..60
        for (int k = 0; k < 2; ++k) {
            int cb = k * 64 + cg;
            float4 v0 = x4[(bb * 128 + cb + 0) * 1024 + tile * 32 + p4];
            float4 v1 = x4[(bb * 128 + cb + 1) * 1024 + tile * 32 + p4];
            float4 v2 = x4[(bb * 128 + cb + 2) * 1024 + tile * 32 + p4];
            float4 v3 = x4[(bb * 128 + cb + 3) * 1024 + tile * 32 + p4];
            float a0[4] = {v0.x, v0.y, v0.z, v0.w};
            float a1[4] = {v1.x, v1.y, v1.z, v1.w};
            float a2[4] = {v2.x, v2.y, v2.z, v2.w};
            float a3[4] = {v3.x, v3.y, v3.z, v3.w};
#pragma unroll
            for (int j = 0; j < 4; ++j) {
                union { unsigned w[2]; s16x4 v; } pk;
                pk.w[0] = cvtpk_bf16(a0[j], a1[j]);   // channels cb, cb+1
                pk.w[1] = cvtpk_bf16(a2[j], a3[j]);   // channels cb+2, cb+3
                *(s16x4*)&xT[(p4 * 4 + j) * 136 + cb] = pk.v;
            }
        }
    }
    __syncthreads();
    int lane = tid & 63, wv = tid >> 6;        // wv 0..7
    int q = lane >> 4, l = lane & 15;
    int pxw = wv * 16;
    f32x4 acc[6];
    const f32x4 z4 = {0.f, 0.f, 0.f, 0.f};
#pragma unroll
    for (int nt = 0; nt < 6; ++nt) acc[nt] = z4;
#pragma unroll
    for (int kk = 0; kk < 4; ++kk) {
        bf16x8 a0 = *(const bf16x8*)&xT[(pxw + l) * 136 + kk * 32 + q * 8];
#pragma unroll
        for (int nt = 0; nt < 6; ++nt) {
            bf16x8 bw = *(const bf16x8*)&wnl[(nt * 16 + l) * 136 + kk * 32 + q * 8];
            acc[nt] = __builtin_amdgcn_mfma_f32_16x16x32_bf16(a0, bw, acc[nt], 0, 0, 0);
        }
    }
    // theta (nt=0): thetaT[s][c], c=l
#pragma unroll
    for (int r = 0; r < 4; ++r) {
        int s = px0 + pxw + q * 4 + r;
        thetaT[(bb * 4096 + s) * 16 + l] = f2b(acc[0][r]);
    }
    __syncthreads();   // all waves done reading wnl
    unsigned short* poolbuf = wnl;   // [80 ch][px] stride 132
#pragma unroll
    for (int nt = 1; nt < 6; ++nt) {
        int ch = nt * 16 + l - 16;
#pragma unroll
        for (int r = 0; r < 4; ++r) {
            poolbuf[ch * 132 + pxw + q * 4 + r] = f2b(acc[nt][r]);
        }
    }
    __syncthreads();
    for (int i = tid; i < 2560; i += 512) {
        int tcol = i & 31, ch = i >> 5;
        int base = ch * 132 + tcol * 2;
        float m0 = fmaxf(b2f(poolbuf[base]), b2f(poolbuf[base + 1]));
        float m1 = fmaxf(b2f(poolbuf[base + 64]), b2f(poolbuf[base + 65]));
        float m = fmaxf(m0, m1);
        int t = tile * 32 + tcol;
        if (ch < 16) phiT[(bb * 1024 + t) * 16 + ch] = f2b(m);
        else         gT[(bb * 64 + ch - 16) * 1024 + t] = f2b(m);
    }
}

// ------- Kernel C: fused attention + output conv + residual -----------------
// grid: 1024 blocks x 256 threads (4 waves = 2 s-groups x 2 t-halves),
// launch_bounds(256,4). g staged via global_load_lds DMA with PRE-SWIZZLED
// per-lane global source + LINEAR LDS dest (rule-21 pattern): slot j of row
// c holds g[c][t0 + (j^(c&7))*8..+7]; read side keeps its XOR. Removes 16
// staging VGPRs + all staging VALU from the wave stream. PV k-groups 0,1
// are issued BEFORE the sb-exp block so the MFMA pipe covers the trans-pipe
// exp cost (separate pipes, m114).
__global__ __launch_bounds__(256, 4) void attn_out(
        const unsigned short* __restrict__ thetaT,
        const unsigned short* __restrict__ phiT,
        const unsigned short* __restrict__ gT,
        const unsigned short* __restrict__ wo,
        const float* __restrict__ x, const float* __restrict__ gam,
        float* __restrict__ out) {
    __shared__ unsigned short gl[2][2][4096];  // [dbuf][t-half][64c x 64t swz] 32KB
    __shared__ float ldsD[2][2][32];
    float* ldsOf = (float*)&gl[0][0][0];       // combine view (post-loop reuse)
    int tid = threadIdx.x;
    // XCD-chunked bijective swizzle (1024 = 8 XCD x 128 chunks)
    int kblk = blockIdx.x;
    int vblk = (kblk & 7) * 128 + (kblk >> 3);
    int bb = vblk >> 6, st = vblk & 63;
    int s0 = st << 6;
    int lane = tid & 63, wv = tid >> 6;
    int sg = wv & 1, sp = wv >> 1;
    int sl = lane & 31, hi = lane >> 5;
    int srow = bb * 4096 + s0 + sg * 32 + sl;      // this lane's s (global)
    const unsigned short* phiB = phiT + bb * 16384;    // [1024][16]
    const unsigned short* gB   = gT + bb * 65536;      // [64][1024]
    int tbase = sp << 9;                               // 0 or 512

    // DMA staging geometry: wave wv stages t-half h = wv>>1, row slab
    // rb = (wv&1)*32 (4 instrs x 8 rows). Lane covers row rb+k*8+(lane>>3),
    // slot j = lane&7; source t-slot = j ^ ((lane>>3)&7) (involution).
    int h = wv >> 1;
    int rb = (wv & 1) * 32;
    int cl = lane >> 3, js = lane & 7;
    const unsigned short* gsl = gB + (rb + cl) * 1024 + h * 512 + ((js ^ cl) * 8);
    // prologue: stage chunk 0 into buf 0
#pragma unroll
    for (int k = 0; k < 4; ++k)
        gload_lds16(gsl + k * 8192, &gl[0][h][(rb + k * 8) * 64]);

    // theta B-frag: B[k=c=hi*8+j][col=s=sl], loop-invariant
    bf16x8 bth = *(const bf16x8*)&thetaT[srow * 16 + hi * 8];

    f32x16 z16;
#pragma unroll
    for (int i = 0; i < 16; ++i) z16[i] = 0.f;
    f32x16 acc0 = z16, acc1 = z16;     // O rows c 0..31 / 32..63, col s=sl
    float lp4[4] = {0.f, 0.f, 0.f, 0.f};

    // phi A-frag 1-deep pipeline: A[row=t][k=c=hi*8+j]
    bf16x8 ph0 = *(const bf16x8*)&phiB[(tbase + sl) * 16 + hi * 8];
    bf16x8 ph1 = *(const bf16x8*)&phiB[(tbase + 32 + sl) * 16 + hi * 8];
    __syncthreads();   // chunk 0 DMA drained by barrier's vmcnt(0)

    int rsw = (sl & 7) << 3;
    for (int tc = 0; tc < 8; ++tc) {
        int buf = tc & 1;
        // issue next-chunk DMA early; full compute phase covers the latency
        if (tc < 7) {
#pragma unroll
            for (int k = 0; k < 4; ++k)
                gload_lds16(gsl + k * 8192 + (tc + 1) * 64,
                            &gl[buf ^ 1][h][(rb + k * 8) * 64]);
        }
        // S^T tile 0: t-block t0+0..31
        f32x16 sa = __builtin_amdgcn_mfma_f32_32x32x16_bf16(ph0, bth, z16, 0, 0, 0);
        unsigned u0[8], u1[8];
#pragma unroll
        for (int i = 0; i < 8; ++i) {
            float e0 = __expf(sa[2 * i]);
            float e1 = __expf(sa[2 * i + 1]);
            lp4[0] += e0; lp4[1] += e1;
            u0[i] = cvtpk_bf16(e0, e1);
        }
        // pin: issue second S-MFMA only after sa is consumed (disjoint
        // sa/sb live ranges -> lower register peak)
        __builtin_amdgcn_sched_barrier(0);
        f32x16 sb = __builtin_amdgcn_mfma_f32_32x32x16_bf16(ph1, bth, z16, 0, 0, 0);
        pl32swap(u0[0], u0[2]); pl32swap(u0[1], u0[3]);
        pl32swap(u0[4], u0[6]); pl32swap(u0[5], u0[7]);
        const unsigned short* glr = &gl[buf][sp][0];
        // PV k-groups 0,1 (u0) on the MFMA pipe while sb-exp runs on trans
        __builtin_amdgcn_s_setprio(1);
        {
            int co = (0 * 16 + hi * 8) ^ rsw;
            bf16x8 gf0 = *(const bf16x8*)&glr[sl * 64 + co];
            bf16x8 gf1 = *(const bf16x8*)&glr[(32 + sl) * 64 + co];
            union { unsigned w[4]; bf16x8 v; } pf = {{u0[0], u0[1], u0[2], u0[3]}};
            acc0 = __builtin_amdgcn_mfma_f32_32x32x16_bf16(gf0, pf.v, acc0, 0, 0, 0);
            acc1 = __builtin_amdgcn_mfma_f32_32x32x16_bf16(gf1, pf.v, acc1, 0, 0, 0);
        }
        {
            int co = (1 * 16 + hi * 8) ^ rsw;
            bf16x8 gf0 = *(const bf16x8*)&glr[sl * 64 + co];
            bf16x8 gf1 = *(const bf16x8*)&glr[(32 + sl) * 64 + co];
            union { unsigned w[4]; bf16x8 v; } pf = {{u0[4], u0[5], u0[6], u0[7]}};
            acc0 = __builtin_amdgcn_mfma_f32_32x32x16_bf16(gf0, pf.v, acc0, 0, 0, 0);
            acc1 = __builtin_amdgcn_mfma_f32_32x32x16_bf16(gf1, pf.v, acc1, 0, 0, 0);
        }
        __builtin_amdgcn_s_setprio(0);
        // next-iter phi prefetch
        int t0n = tbase + (((tc + 1) & 7) << 6);
        ph0 = *(const bf16x8*)&phiB[(t0n + sl) * 16 + hi * 8];
        ph1 = *(const bf16x8*)&phiB[(t0n + 32 + sl) * 16 + hi * 8];
#pragma unroll
        for (int i = 0; i < 8; ++i) {
            float e2 = __expf(sb[2 * i]);
            float e3 = __expf(sb[2 * i + 1]);
            lp4[2] += e2; lp4[3] += e3;
            u1[i] = cvtpk_bf16(e2, e3);
        }
        pl32swap(u1[0], u1[2]); pl32swap(u1[1], u1[3]);
        pl32swap(u1[4], u1[6]); pl32swap(u1[5], u1[7]);
        __builtin_amdgcn_s_setprio(1);
        {
            int co = (2 * 16 + hi * 8) ^ rsw;
            bf16x8 gf0 = *(const bf16x8*)&glr[sl * 64 + co];
            bf16x8 gf1 = *(const bf16x8*)&glr[(32 + sl) * 64 + co];
            union { unsigned w[4]; bf16x8 v; } pf = {{u1[0], u1[1], u1[2], u1[3]}};
            acc0 = __builtin_amdgcn_mfma_f32_32x32x16_bf16(gf0, pf.v, acc0, 0, 0, 0);
            acc1 = __builtin_amdgcn_mfma_f32_32x32x16_bf16(gf1, pf.v, acc1, 0, 0, 0);
        }
        {
            int co = (3 * 16 + hi * 8) ^ rsw;
            bf16x8 gf0 = *(const bf16x8*)&glr[sl * 64 + co];
            bf16x8 gf1 = *(const bf16x8*)&glr[(32 + sl) * 64 + co];
            union { unsigned w[4]; bf16x8 v; } pf = {{u1[4], u1[5], u1[6], u1[7]}};
            acc0 = __builtin_amdgcn_mfma_f32_32x32x16_bf16(gf0, pf.v, acc0, 0, 0, 0);
            acc1 = __builtin_amdgcn_mfma_f32_32x32x16_bf16(gf1, pf.v, acc1, 0, 0, 0);
        }
        __builtin_amdgcn_s_setprio(0);
        // barrier: gates DMA completion (vmcnt drain) for next iter's reads
        // AND protects buf from being re-written while still being read
        if (tc < 7) __syncthreads();
    }
    __syncthreads();   // all PV reads done before gl is reused as ldsOf

    // per-lane partial denominator (s = sl): reduce own 4 + partner half
    float tot = (lp4[0] + lp4[1]) + (lp4[2] + lp4[3]);
    tot += __shfl_xor(tot, 32);

    // cross-split exchange via LDS: both sp halves write partials, both
    // combine (each wave ends with the full normalized O words).
#pragma unroll
    for (int i = 0; i < 16; ++i) {
        int c = (i & 3) + 8 * (i >> 2) + 4 * hi;
        ldsOf[(sg * 2 + sp) * 2048 + c * 32 + sl] = acc0[i];
        ldsOf[(sg * 2 + sp) * 2048 + (32 + c) * 32 + sl] = acc1[i];
    }
    if (hi == 0) ldsD[sg][sp][sl] = tot;
    // Wo A-frags for this wave's oc half (issued before the barrier so the
    // loads fly during the LDS exchange). aw[mt][ch] = Wo[sp*64+mt*32+sl][ch*16+hi*8..]
    bf16x8 aw[2][4];
#pragma unroll
    for (int mt = 0; mt < 2; ++mt)
#pragma unroll
        for (int ch = 0; ch < 4; ++ch)
            aw[mt][ch] = *(const bf16x8*)&wo[(sp * 64 + mt * 32 + sl) * 64 + ch * 16 + hi * 8];
    __syncthreads();
    int osp = sp ^ 1;
    tot += ldsD[sg][osp][sl];
    float inv = 1.0f / tot;
#pragma unroll
    for (int i = 0; i < 16; ++i) {
        int c = (i & 3) + 8 * (i >> 2) + 4 * hi;
        acc0[i] += ldsOf[(sg * 2 + osp) * 2048 + c * 32 + sl];
        acc1[i] += ldsOf[(sg * 2 + osp) * 2048 + (32 + c) * 32 + sl];
    }
    // normalized O -> bf16 B-frags of out = Wo @ O (verified rounds 2-6)
    unsigned o0[8], o1[8];
#pragma unroll
    for (int i = 0; i < 8; ++i) {
        o0[i] = cvtpk_bf16(acc0[2 * i] * inv, acc0[2 * i + 1] * inv);
        o1[i] = cvtpk_bf16(acc1[2 * i] * inv, acc1[2 * i + 1] * inv);
    }
    pl32swap(o0[0], o0[2]); pl32swap(o0[1], o0[3]);
    pl32swap(o0[4], o0[6]); pl32swap(o0[5], o0[7]);
    pl32swap(o1[0], o1[2]); pl32swap(o1[1], o1[3]);
    pl32swap(o1[4], o1[6]); pl32swap(o1[5], o1[7]);
    bf16x8 bfr[4];
    {
        union { unsigned w[4]; bf16x8 v; } t;
        t.w[0] = o0[0]; t.w[1] = o0[1]; t.w[2] = o0[2]; t.w[3] = o0[3]; bfr[0] = t.v;
        t.w[0] = o0[4]; t.w[1] = o0[5]; t.w[2] = o0[6]; t.w[3] = o0[7]; bfr[1] = t.v;
        t.w[0] = o1[0]; t.w[1] = o1[1]; t.w[2] = o1[2]; t.w[3] = o1[3]; bfr[2] = t.v;
        t.w[0] = o1[4]; t.w[1] = o1[5]; t.w[2] = o1[6]; t.w[3] = o1[7]; bfr[3] = t.v;
    }
    // out = Wo @ O for this wave's 64 oc rows (2 m-tiles of 32)
    f32x16 d0 = z16, d1 = z16;
#pragma unroll
    for (int ch = 0; ch < 4; ++ch) {
        d0 = __builtin_amdgcn_mfma_f32_32x32x16_bf16(aw[0][ch], bfr[ch], d0, 0, 0, 0);
        d1 = __builtin_amdgcn_mfma_f32_32x32x16_bf16(aw[1][ch], bfr[ch], d1, 0, 0, 0);
    }
    // write gamma*D + x.  D row = oc_local = (i&3)+8*(i>>2)+4*hi, col = s=sl
    float gm = gam[0];
    int scol = s0 + sg * 32 + sl;
#pragma unroll
    for (int i = 0; i < 16; ++i) {
        int r = (i & 3) + 8 * (i >> 2) + 4 * hi;
        int a0 = (bb * 128 + sp * 64 + r) * 4096 + scol;
        int a1 = (bb * 128 + sp * 64 + 32 + r) * 4096 + scol;
        out[a0] = gm * d0[i] + x[a0];
        out[a1] = gm * d1[i] + x[a1];
    }
}

extern "C" void kernel_launch(void* const* d_in, const int* in_sizes, int n_in,
                              void* d_out, int out_size, void* d_ws, size_t ws_size,
                              hipStream_t stream) {
    const float* x  = (const float*)d_in[0];
    const float* wt = (const float*)d_in[1];
    const float* wp = (const float*)d_in[2];
    const float* wg = (const float*)d_in[3];
    const float* wo = (const float*)d_in[4];
    const float* ut = (const float*)d_in[5];
    const float* up = (const float*)d_in[6];
    const float* ug = (const float*)d_in[7];
    const float* uo = (const float*)d_in[8];
    const float* gm = (const float*)d_in[9];
    unsigned short* wsu = (unsigned short*)d_ws;
    float* out = (float*)d_out;

    sn4<<<4, 256, 0, stream>>>(wt, wp, wg, wo, ut, up, ug, uo, wsu);
    convpool_mfma<<<512, 512, 0, stream>>>(x, wsu + U_WN,
                                           wsu + U_TH, wsu + U_PHI, wsu + U_G);
    attn_out<<<1024, 256, 0, stream>>>(wsu + U_TH, wsu + U_PHI, wsu + U_G,
                                       wsu + U_WO, x, gm, out);
}